// Round 9
// baseline (433.839 us; speedup 1.0000x reference)
//
#include <hip/hip_runtime.h>
#include <hip/hip_bf16.h>
#include <hip/hip_cooperative_groups.h>
#include <stdint.h>

namespace cg = cooperative_groups;

#define IN_DIM 256
#define HID 16
#define OUTD 10
#define BKT_SHIFT 8            // 256 nodes per bucket
#define BKT_W 256
#define PART_CH 4096           // edges per partition block (best measured)
#define EPT 16                 // edges per thread in part
#define G_HIST 512             // histogram blocks in K1
#define SSRC_CAP 8704          // fallback-kernel LDS src capacity
#define SSRC_CAP2 9216         // cooperative-kernel LDS src capacity (+11 sigma)

typedef short v8s __attribute__((ext_vector_type(8)));
typedef float v4f __attribute__((ext_vector_type(4)));

__device__ __forceinline__ float bf2f(unsigned short u) {
    return __uint_as_float(((unsigned int)u) << 16);
}
__device__ __forceinline__ unsigned short f2bf(float f) {
    unsigned int u = __float_as_uint(f);
    unsigned int lsb = (u >> 16) & 1u;
    u += 0x7fffu + lsb;  // round-to-nearest-even
    return (unsigned short)(u >> 16);
}

__device__ __forceinline__ int load_dst(const void* ei, int n_edges, int e, int is64) {
    return is64 ? (int)((const long long*)ei)[(size_t)n_edges + e]
                : ((const int*)ei)[(size_t)n_edges + e];
}
__device__ __forceinline__ int load_src(const void* ei, int n_edges, int e, int is64) {
    return is64 ? (int)((const long long*)ei)[e] : ((const int*)ei)[e];
}

// ---------------- zero: bucket counters (plain kernel, no memset API) -------
__global__ void zero_kernel(int* __restrict__ bucket_cnt, int K) {
    for (int i = threadIdx.x; i < K; i += blockDim.x) bucket_cnt[i] = 0;
}

// ---------------- K1 fat: setup/flags/W1-split (17 blocks) + bhist ----------
__global__ void setup_bhist_kernel(const void* __restrict__ x,
                                   const void* __restrict__ W1,
                                   const void* __restrict__ ei,
                                   int n_nodes, int n_edges,
                                   int* __restrict__ flags,
                                   int* __restrict__ bucket_cnt, int K,
                                   unsigned short* __restrict__ W1split) {
    __shared__ int lh[512];
    __shared__ int sflag;
    int b = blockIdx.x, t = threadIdx.x;

    if (b < 16) {
        // ---- W1 split role (local wf32 detect over first 256 values) ----
        if (t == 0) sflag = 0;
        __syncthreads();
        {
            float vw = bf2f(((const unsigned short*)W1)[t]);
            if (!(vw > -1e4f && vw < 1e4f)) sflag = 1;   // benign same-value race
        }
        __syncthreads();
        const int wf32 = sflag;
        int i = b * 256 + t;                       // 0..4095 (i = k*16 + n)
        float w = wf32 ? ((const float*)W1)[i]
                       : bf2f(((const unsigned short*)W1)[i]);
        unsigned short hi = f2bf(w);
        unsigned short lo = f2bf(w - bf2f(hi));
        int k = i >> 4, n = i & 15;
        int kk = k >> 5, qd = (k >> 3) & 3, j = k & 7;
        int idx = ((kk * 4 + qd) * 16 + n) * 8 + j;  // = (kk*64 + lane)*8 + j
        W1split[idx] = hi;
        W1split[4096 + idx] = lo;
        return;
    }
    if (b == 16) {
        // ---- global flags role ----
        if (t < 64) {
            const unsigned short* xs = (const unsigned short*)x;
            const unsigned short* ws = (const unsigned short*)W1;
            bool badx = false, badw = false;
#pragma unroll
            for (int q = 0; q < 4; ++q) {
                float vx = bf2f(xs[t + 64 * q]);
                float vw = bf2f(ws[t + 64 * q]);
                if (!(vx > -1e4f && vx < 1e4f)) badx = true;
                if (!(vw > -1e4f && vw < 1e4f)) badw = true;
            }
            const unsigned long long* e64 = (const unsigned long long*)ei;
            bool big = false;
#pragma unroll
            for (int q = 0; q < 2; ++q)
                if (e64[t + 64 * q] >= (unsigned long long)n_nodes) big = true;
            int xf32 = __any(badx) ? 1 : 0;
            int wf32 = __any(badw) ? 1 : 0;
            int is64 = __any(big) ? 0 : 1;
            if (t == 0) { flags[0] = is64; flags[1] = xf32; flags[2] = wf32; }
        }
        return;
    }

    // ---- bhist role (local is64 detect over first 128 u64 reads) ----
    if (t == 0) sflag = 1;
    __syncthreads();
    {
        const unsigned long long* e64 = (const unsigned long long*)ei;
        if (t < 128 && e64[t] >= (unsigned long long)n_nodes) sflag = 0;
    }
    __syncthreads();
    const int is64 = sflag;
    for (int i = t; i < 512; i += 256) lh[i] = 0;
    __syncthreads();
    int vbid = b - 17;
    int stride = G_HIST * 256;
    for (int e = vbid * 256 + t; e < n_edges; e += stride) {
        int d = load_dst(ei, n_edges, e, is64);
        atomicAdd(&lh[d >> BKT_SHIFT], 1);
    }
    __syncthreads();
    for (int i = t; i < K; i += 256)
        if (lh[i]) atomicAdd(&bucket_cnt[i], lh[i]);
}

// ---------------- bucket scan (1 block) -------------------------------------
__global__ void bscan_kernel(const int* __restrict__ bucket_cnt, int K,
                             int* __restrict__ bucket_off, int* __restrict__ bcur,
                             int* __restrict__ row_off, int n_nodes, int n_edges) {
    __shared__ int ts[256];
    int t = threadIdx.x;
    const int KP = (K + 255) / 256;   // <= 8
    int base = t * KP;
    int local[8];
    int s = 0;
    for (int q = 0; q < KP; ++q) {
        int idx = base + q;
        int v = (idx < K) ? bucket_cnt[idx] : 0;
        local[q] = v; s += v;
    }
    ts[t] = s;
    __syncthreads();
    for (int off = 1; off < 256; off <<= 1) {
        int v = (t >= off) ? ts[t - off] : 0;
        __syncthreads();
        ts[t] += v;
        __syncthreads();
    }
    int ex = ts[t] - s;
    for (int q = 0; q < KP; ++q) {
        int idx = base + q;
        if (idx < K) { bucket_off[idx] = ex; bcur[idx] = ex; }
        ex += local[q];
    }
    if (t == 255) bucket_off[K] = ex;
    if (t == 0) row_off[n_nodes] = n_edges;
}

// ---------------- K2 fat: part (blocks < g_part) + gemm1 --------------------
__global__ __launch_bounds__(256, 4) void part_gemm1_kernel(
        const void* __restrict__ ei, int n_edges,
        int* __restrict__ bcur, unsigned int* __restrict__ pairs,
        const void* __restrict__ xp_,
        const unsigned short* __restrict__ W1split,
        unsigned short* __restrict__ m1, int n_nodes,
        const int* __restrict__ flags, int K, int g_part) {
    __shared__ int lh[512];                  // counts, then placement cursor
    __shared__ int gdelta[512];              // gstart[b] - lstart[b]
    __shared__ int ts[256];
    __shared__ unsigned int spairs[PART_CH]; // 16 KiB
    __shared__ unsigned short sbkt[PART_CH]; // 8 KiB
    int t = threadIdx.x;

    if ((int)blockIdx.x < g_part) {
        // ---------- partition role ----------
        int begin = blockIdx.x * PART_CH;
        int is64 = flags[0];
        lh[t] = 0; lh[t + 256] = 0;

        int dloc[EPT];
#pragma unroll
        for (int i = 0; i < EPT; ++i) {
            int e = begin + i * 256 + t;
            dloc[i] = (e < n_edges) ? load_dst(ei, n_edges, e, is64) : -1;
        }
        __syncthreads();
#pragma unroll
        for (int i = 0; i < EPT; ++i)
            if (dloc[i] >= 0) atomicAdd(&lh[dloc[i] >> BKT_SHIFT], 1);
        __syncthreads();

        // block scan over 512 bucket counts (thread t owns entries 2t, 2t+1)
        int c0 = lh[2 * t], c1 = lh[2 * t + 1];
        int s = c0 + c1;
        ts[t] = s;
        __syncthreads();
        for (int off = 1; off < 256; off <<= 1) {
            int v = (t >= off) ? ts[t - off] : 0;
            __syncthreads();
            ts[t] += v;
            __syncthreads();
        }
        int ex = ts[t] - s;
        if (c0 > 0) gdelta[2 * t]     = atomicAdd(&bcur[2 * t], c0) - ex;
        if (c1 > 0) gdelta[2 * t + 1] = atomicAdd(&bcur[2 * t + 1], c1) - (ex + c0);
        __syncthreads();
        lh[2 * t] = ex; lh[2 * t + 1] = ex + c0;
        __syncthreads();

#pragma unroll
        for (int i = 0; i < EPT; ++i) {
            int e = begin + i * 256 + t;
            if (dloc[i] >= 0) {
                int srcv = load_src(ei, n_edges, e, is64);
                int bb = dloc[i] >> BKT_SHIFT;
                int lpos = atomicAdd(&lh[bb], 1);
                spairs[lpos] = ((unsigned)srcv << 8) | ((unsigned)dloc[i] & (BKT_W - 1));
                sbkt[lpos] = (unsigned short)bb;
            }
        }
        __syncthreads();

        int total = n_edges - begin; if (total > PART_CH) total = PART_CH;
        for (int j = t; j < total; j += 256)
            pairs[gdelta[sbkt[j]] + j] = spairs[j];
        return;
    }

    // ---------- gemm1 role ----------
    const int xf32 = flags[1];
    int vb = blockIdx.x - g_part;
    int g_gemm = gridDim.x - g_part;
    int lane = t & 63;
    int wave = t >> 6;
    int col  = lane & 15;
    int quad = lane >> 4;
    int n_tiles = (n_nodes + 15) >> 4;
    const unsigned short* Whi = W1split;
    const unsigned short* Wlo = W1split + 4096;

    if (!xf32) {
        const unsigned short* x = (const unsigned short*)xp_;
        for (int tile = vb * 4 + wave; tile < n_tiles; tile += g_gemm * 4) {
            int row = tile * 16 + col;
            int r = row < n_nodes ? row : n_nodes - 1;
            const unsigned short* xp = x + (size_t)r * IN_DIM + quad * 8;
            v8s a[8];
#pragma unroll
            for (int kk = 0; kk < 8; ++kk)
                a[kk] = *(const v8s*)(xp + kk * 32);
            v4f acc1 = {0.f, 0.f, 0.f, 0.f};
            v4f acc2 = {0.f, 0.f, 0.f, 0.f};
#pragma unroll
            for (int kk = 0; kk < 8; ++kk) {
                v8s bh = *(const v8s*)&Whi[(kk * 64 + lane) * 8];
                v8s bl = *(const v8s*)&Wlo[(kk * 64 + lane) * 8];
                acc1 = __builtin_amdgcn_mfma_f32_16x16x32_bf16(a[kk], bh, acc1, 0, 0, 0);
                acc2 = __builtin_amdgcn_mfma_f32_16x16x32_bf16(a[kk], bl, acc2, 0, 0, 0);
            }
#pragma unroll
            for (int rg = 0; rg < 4; ++rg) {
                int node = tile * 16 + quad * 4 + rg;
                if (node < n_nodes)
                    m1[(size_t)node * HID + col] = f2bf(acc1[rg] + acc2[rg]);
            }
        }
    } else {
        const float* x = (const float*)xp_;
        for (int tile = vb * 4 + wave; tile < n_tiles; tile += g_gemm * 4) {
            int row = tile * 16 + col;
            int r = row < n_nodes ? row : n_nodes - 1;
            const float* xp = x + (size_t)r * IN_DIM + quad * 8;
            float4 u[16];
#pragma unroll
            for (int kk = 0; kk < 8; ++kk) {
                u[2 * kk]     = *(const float4*)(xp + kk * 32);
                u[2 * kk + 1] = *(const float4*)(xp + kk * 32 + 4);
            }
            v4f acc1 = {0.f, 0.f, 0.f, 0.f};   // ahi*bh chain
            v4f acc2 = {0.f, 0.f, 0.f, 0.f};   // ahi*bl + alo*bh chain
#pragma unroll
            for (int kk = 0; kk < 8; ++kk) {
                float uv[8] = {u[2 * kk].x,     u[2 * kk].y,
                               u[2 * kk].z,     u[2 * kk].w,
                               u[2 * kk + 1].x, u[2 * kk + 1].y,
                               u[2 * kk + 1].z, u[2 * kk + 1].w};
                v8s ahi, alo;
#pragma unroll
                for (int j = 0; j < 8; ++j) {
                    unsigned short hi = f2bf(uv[j]);
                    unsigned short lo = f2bf(uv[j] - bf2f(hi));
                    ahi[j] = (short)hi; alo[j] = (short)lo;
                }
                v8s bh = *(const v8s*)&Whi[(kk * 64 + lane) * 8];
                v8s bl = *(const v8s*)&Wlo[(kk * 64 + lane) * 8];
                acc1 = __builtin_amdgcn_mfma_f32_16x16x32_bf16(ahi, bh, acc1, 0, 0, 0);
                acc2 = __builtin_amdgcn_mfma_f32_16x16x32_bf16(ahi, bl, acc2, 0, 0, 0);
                acc2 = __builtin_amdgcn_mfma_f32_16x16x32_bf16(alo, bh, acc2, 0, 0, 0);
            }
#pragma unroll
            for (int rg = 0; rg < 4; ++rg) {
                int node = tile * 16 + quad * 4 + rg;
                if (node < n_nodes)
                    m1[(size_t)node * HID + col] = f2bf(acc1[rg] + acc2[rg]);
            }
        }
    }
}

// ---------------- K3 cooperative: csr+agg1 | grid.sync | agg2+out -----------
// One block per bucket (391 <= 4 blocks/CU x 256 CUs co-resident; coop needs
// only 2/CU). Phase B builds the bucket's grouped src list in LDS (global
// spill for >SSRC_CAP2 buckets only) and aggregates h = relu(A.m1 + b1).
// grid.sync() (device-scope fenced) then phase C aggregates out =
// (A.h)@W2 + b2 reading the STILL-RESIDENT LDS src list -> the 12.8MB
// csr_src write + 12.8MB re-read + row_off read + one launch all disappear.
__global__ __launch_bounds__(512, 4) void csr_agg12_kernel(
        const unsigned int* __restrict__ pairs,
        const int* __restrict__ bucket_off,
        const unsigned short* __restrict__ m1,
        const void* __restrict__ b1p,
        const void* __restrict__ W2p,
        const void* __restrict__ b2p,
        int* __restrict__ spill,
        unsigned short* __restrict__ h,
        void* __restrict__ out,
        int n_nodes, const int* __restrict__ flags) {
    __shared__ int deg[BKT_W];
    __shared__ int cur[BKT_W];
    __shared__ int ts[BKT_W];
    __shared__ float wsb[192];                 // [0..159]=W2, [160..169]=b2, [176..191]=b1
    __shared__ unsigned int ssrc[SSRC_CAP2];   // 36 KiB grouped src list
    cg::grid_group grid = cg::this_grid();

    int blk = blockIdx.x;
    int nbase = blk << BKT_SHIFT;
    int NL = n_nodes - nbase; if (NL > BKT_W) NL = BKT_W; if (NL < 0) NL = 0;
    int beg = bucket_off[blk], end = bucket_off[blk + 1];
    int t = threadIdx.x;
    const int xf32 = flags[1], wf32 = flags[2];

    // weights -> LDS (persist through both phases)
    if (t < HID * OUTD)
        wsb[t] = wf32 ? ((const float*)W2p)[t] : bf2f(((const unsigned short*)W2p)[t]);
    if (t >= 256 && t < 256 + OUTD) {
        int i = t - 256;
        wsb[160 + i] = wf32 ? ((const float*)b2p)[i] : bf2f(((const unsigned short*)b2p)[i]);
    }
    if (t >= 288 && t < 288 + HID) {
        int i = t - 288;
        wsb[176 + i] = wf32 ? ((const float*)b1p)[i] : bf2f(((const unsigned short*)b1p)[i]);
    }
    if (t < BKT_W) deg[t] = 0;
    __syncthreads();

    // ---- csr build into LDS ----
    for (int k = beg + t; k < end; k += 512)
        atomicAdd(&deg[pairs[k] & (BKT_W - 1)], 1);
    __syncthreads();
    if (t < BKT_W) ts[t] = deg[t];
    __syncthreads();
    for (int off = 1; off < BKT_W; off <<= 1) {
        int v = 0;
        if (t < BKT_W && t >= off) v = ts[t - off];
        __syncthreads();
        if (t < BKT_W) ts[t] += v;
        __syncthreads();
    }
    if (t < BKT_W) cur[t] = ts[t] - deg[t];
    __syncthreads();
    for (int k = beg + t; k < end; k += 512) {
        unsigned int pr = pairs[k];
        int dl = pr & (BKT_W - 1);
        int pos = atomicAdd(&cur[dl], 1);
        int src = (int)(pr >> 8);
        if (pos < SSRC_CAP2) ssrc[pos] = (unsigned)src;
        else spill[beg + pos] = src;
    }
    __syncthreads();

    // ---- phase B: agg1 -> h = bf16(relu(sum m1[src] + b1)) ----
    int q = t & 3, grp = t >> 2;
    {
        float b0 = wsb[176 + q * 4 + 0], b1v = wsb[176 + q * 4 + 1];
        float b2v = wsb[176 + q * 4 + 2], b3 = wsb[176 + q * 4 + 3];
        for (int nl = grp; nl < NL; nl += 128) {
            int sL = ts[nl] - deg[nl];
            int eL = ts[nl];
            float a0 = 0.f, a1 = 0.f, a2 = 0.f, a3 = 0.f;
            int k = sL;
            for (; k + 8 <= eL; k += 8) {
                int sidx[8];
                uint2 v[8];
#pragma unroll
                for (int u = 0; u < 8; ++u)
                    sidx[u] = (k + u < SSRC_CAP2) ? (int)ssrc[k + u]
                                                  : spill[beg + k + u];
#pragma unroll
                for (int u = 0; u < 8; ++u)
                    v[u] = *(const uint2*)(m1 + (size_t)sidx[u] * HID + q * 4);
#pragma unroll
                for (int u = 0; u < 8; ++u) {
                    a0 += bf2f((unsigned short)(v[u].x));
                    a1 += bf2f((unsigned short)(v[u].x >> 16));
                    a2 += bf2f((unsigned short)(v[u].y));
                    a3 += bf2f((unsigned short)(v[u].y >> 16));
                }
            }
            for (; k < eL; ++k) {
                int s = (k < SSRC_CAP2) ? (int)ssrc[k] : spill[beg + k];
                uint2 v = *(const uint2*)(m1 + (size_t)s * HID + q * 4);
                a0 += bf2f((unsigned short)(v.x));
                a1 += bf2f((unsigned short)(v.x >> 16));
                a2 += bf2f((unsigned short)(v.y));
                a3 += bf2f((unsigned short)(v.y >> 16));
            }
            float r0 = fmaxf(a0 + b0, 0.f);
            float r1 = fmaxf(a1 + b1v, 0.f);
            float r2 = fmaxf(a2 + b2v, 0.f);
            float r3 = fmaxf(a3 + b3, 0.f);
            uint2 packed;
            packed.x = (unsigned int)f2bf(r0) | ((unsigned int)f2bf(r1) << 16);
            packed.y = (unsigned int)f2bf(r2) | ((unsigned int)f2bf(r3) << 16);
            *(uint2*)(h + (size_t)(nbase + nl) * HID + q * 4) = packed;
        }
    }

    __threadfence();      // make h visible device-wide (cross-XCD)
    grid.sync();

    // ---- phase C: agg2 + out = (A.h)@W2 + b2, src list still in LDS ----
    for (int nl = grp; nl < NL; nl += 128) {
        int sL = ts[nl] - deg[nl];
        int eL = ts[nl];
        float a0 = 0.f, a1 = 0.f, a2 = 0.f, a3 = 0.f;
        int k = sL;
        for (; k + 8 <= eL; k += 8) {
            int sidx[8];
            uint2 v[8];
#pragma unroll
            for (int u = 0; u < 8; ++u)
                sidx[u] = (k + u < SSRC_CAP2) ? (int)ssrc[k + u]
                                              : spill[beg + k + u];
#pragma unroll
            for (int u = 0; u < 8; ++u)
                v[u] = *(const uint2*)(h + (size_t)sidx[u] * HID + q * 4);
#pragma unroll
            for (int u = 0; u < 8; ++u) {
                a0 += bf2f((unsigned short)(v[u].x));
                a1 += bf2f((unsigned short)(v[u].x >> 16));
                a2 += bf2f((unsigned short)(v[u].y));
                a3 += bf2f((unsigned short)(v[u].y >> 16));
            }
        }
        for (; k < eL; ++k) {
            int s = (k < SSRC_CAP2) ? (int)ssrc[k] : spill[beg + k];
            uint2 v = *(const uint2*)(h + (size_t)s * HID + q * 4);
            a0 += bf2f((unsigned short)(v.x));
            a1 += bf2f((unsigned short)(v.x >> 16));
            a2 += bf2f((unsigned short)(v.y));
            a3 += bf2f((unsigned short)(v.y >> 16));
        }
        float av[4] = {a0, a1, a2, a3};
        float o[OUTD];
#pragma unroll
        for (int od = 0; od < OUTD; ++od) {
            float s = 0.f;
#pragma unroll
            for (int j = 0; j < 4; ++j)
                s = fmaf(av[j], wsb[(q * 4 + j) * OUTD + od], s);
            o[od] = s;
        }
#pragma unroll
        for (int od = 0; od < OUTD; ++od) {
            o[od] += __shfl_xor(o[od], 1);
            o[od] += __shfl_xor(o[od], 2);
            o[od] += wsb[160 + od];
        }
        int node = nbase + nl;
        if (xf32) {
            float2* po = (float2*)((float*)out + (size_t)node * OUTD);
            if (q == 0) {
                po[0] = make_float2(o[0], o[1]);
                po[1] = make_float2(o[2], o[3]);
            } else if (q == 1) {
                po[2] = make_float2(o[4], o[5]);
                po[3] = make_float2(o[6], o[7]);
            } else if (q == 2) {
                po[4] = make_float2(o[8], o[9]);
            }
        } else {
            unsigned int* po = (unsigned int*)((unsigned short*)out + (size_t)node * OUTD);
            if (q == 0) {
                po[0] = (unsigned int)f2bf(o[0]) | ((unsigned int)f2bf(o[1]) << 16);
                po[1] = (unsigned int)f2bf(o[2]) | ((unsigned int)f2bf(o[3]) << 16);
            } else if (q == 1) {
                po[2] = (unsigned int)f2bf(o[4]) | ((unsigned int)f2bf(o[5]) << 16);
                po[3] = (unsigned int)f2bf(o[6]) | ((unsigned int)f2bf(o[7]) << 16);
            } else if (q == 2) {
                po[4] = (unsigned int)f2bf(o[8]) | ((unsigned int)f2bf(o[9]) << 16);
            }
        }
    }
}

// ================= fallback path (round-8 proven kernels) ===================
__global__ __launch_bounds__(512) void csr_agg1_kernel(
        const unsigned int* __restrict__ pairs,
        const int* __restrict__ bucket_off,
        const unsigned short* __restrict__ m1,
        const void* __restrict__ b1p,
        int* __restrict__ row_off, int* __restrict__ csr_src,
        unsigned short* __restrict__ h,
        int n_nodes, const int* __restrict__ flags) {
    __shared__ unsigned int ssrc[SSRC_CAP];
    __shared__ int deg[BKT_W];
    __shared__ int cur[BKT_W];
    __shared__ int ts[BKT_W];
    int blk = blockIdx.x;
    int nbase = blk << BKT_SHIFT;
    int NL = n_nodes - nbase; if (NL > BKT_W) NL = BKT_W;
    int beg = bucket_off[blk], end = bucket_off[blk + 1];
    int t = threadIdx.x;

    if (t < BKT_W) deg[t] = 0;
    __syncthreads();
    for (int k = beg + t; k < end; k += 512)
        atomicAdd(&deg[pairs[k] & (BKT_W - 1)], 1);
    __syncthreads();
    if (t < BKT_W) ts[t] = deg[t];
    __syncthreads();
    for (int off = 1; off < BKT_W; off <<= 1) {
        int v = 0;
        if (t < BKT_W && t >= off) v = ts[t - off];
        __syncthreads();
        if (t < BKT_W) ts[t] += v;
        __syncthreads();
    }
    if (t < BKT_W) {
        int exl = ts[t] - deg[t];
        cur[t] = exl;
        if (t < NL) row_off[nbase + t] = beg + exl;
    }
    __syncthreads();
    for (int k = beg + t; k < end; k += 512) {
        unsigned int pr = pairs[k];
        int dl = pr & (BKT_W - 1);
        int pos = atomicAdd(&cur[dl], 1);
        int src = (int)(pr >> 8);
        csr_src[beg + pos] = src;
        if (pos < SSRC_CAP) ssrc[pos] = (unsigned)src;
    }
    __syncthreads();

    const int wf32 = flags[2];
    int q = t & 3, grp = t >> 2;
    float b0, b1v, b2v, b3;
    if (wf32) {
        const float* b = (const float*)b1p + q * 4;
        b0 = b[0]; b1v = b[1]; b2v = b[2]; b3 = b[3];
    } else {
        const unsigned short* b = (const unsigned short*)b1p + q * 4;
        b0 = bf2f(b[0]); b1v = bf2f(b[1]); b2v = bf2f(b[2]); b3 = bf2f(b[3]);
    }
    for (int nl = grp; nl < NL; nl += 128) {
        int sL = ts[nl] - deg[nl];
        int eL = ts[nl];
        float a0 = 0.f, a1 = 0.f, a2 = 0.f, a3 = 0.f;
        for (int k = sL; k < eL; ++k) {
            int s = (k < SSRC_CAP) ? (int)ssrc[k] : csr_src[beg + k];
            uint2 v = *(const uint2*)(m1 + (size_t)s * HID + q * 4);
            a0 += bf2f((unsigned short)(v.x));
            a1 += bf2f((unsigned short)(v.x >> 16));
            a2 += bf2f((unsigned short)(v.y));
            a3 += bf2f((unsigned short)(v.y >> 16));
        }
        float r0 = fmaxf(a0 + b0, 0.f);
        float r1 = fmaxf(a1 + b1v, 0.f);
        float r2 = fmaxf(a2 + b2v, 0.f);
        float r3 = fmaxf(a3 + b3, 0.f);
        uint2 packed;
        packed.x = (unsigned int)f2bf(r0) | ((unsigned int)f2bf(r1) << 16);
        packed.y = (unsigned int)f2bf(r2) | ((unsigned int)f2bf(r3) << 16);
        *(uint2*)(h + (size_t)(nbase + nl) * HID + q * 4) = packed;
    }
}

__device__ __forceinline__ v4f gather_bf16(const unsigned short* __restrict__ src,
                                           const int* __restrict__ csr_src,
                                           int beg, int end, int q) {
    float a0 = 0.f, a1 = 0.f, a2 = 0.f, a3 = 0.f;
    int k = beg;
    for (; k + 16 <= end; k += 16) {
        uint2 v[16];
#pragma unroll
        for (int u = 0; u < 16; ++u) {
            int s = csr_src[k + u];
            v[u] = *(const uint2*)(src + (size_t)s * HID + q * 4);
        }
#pragma unroll
        for (int u = 0; u < 16; ++u) {
            a0 += bf2f((unsigned short)(v[u].x));
            a1 += bf2f((unsigned short)(v[u].x >> 16));
            a2 += bf2f((unsigned short)(v[u].y));
            a3 += bf2f((unsigned short)(v[u].y >> 16));
        }
    }
    for (; k < end; ++k) {
        int s = csr_src[k];
        uint2 v = *(const uint2*)(src + (size_t)s * HID + q * 4);
        a0 += bf2f((unsigned short)(v.x));
        a1 += bf2f((unsigned short)(v.x >> 16));
        a2 += bf2f((unsigned short)(v.y));
        a3 += bf2f((unsigned short)(v.y >> 16));
    }
    v4f r = {a0, a1, a2, a3};
    return r;
}

__global__ void agg2_out_kernel(const unsigned short* __restrict__ h,
                                const int* __restrict__ row_off,
                                const int* __restrict__ csr_src,
                                const void* __restrict__ W2p,
                                const void* __restrict__ b2p,
                                void* __restrict__ out, int n_nodes,
                                const int* __restrict__ flags) {
    __shared__ float Ws[HID * OUTD];
    __shared__ float bs[OUTD];
    const int xf32 = flags[1], wf32 = flags[2];
    if (threadIdx.x < HID * OUTD)
        Ws[threadIdx.x] = wf32 ? ((const float*)W2p)[threadIdx.x]
                               : bf2f(((const unsigned short*)W2p)[threadIdx.x]);
    if (threadIdx.x < OUTD)
        bs[threadIdx.x] = wf32 ? ((const float*)b2p)[threadIdx.x]
                               : bf2f(((const unsigned short*)b2p)[threadIdx.x]);
    __syncthreads();

    int t = blockIdx.x * blockDim.x + threadIdx.x;
    int node = t >> 2;
    if (node >= n_nodes) return;
    int q = t & 3;
    v4f a = gather_bf16(h, csr_src, row_off[node], row_off[node + 1], q);

    float o[OUTD];
#pragma unroll
    for (int od = 0; od < OUTD; ++od) {
        float s = 0.f;
#pragma unroll
        for (int j = 0; j < 4; ++j)
            s = fmaf(a[j], Ws[(q * 4 + j) * OUTD + od], s);
        o[od] = s;
    }
#pragma unroll
    for (int od = 0; od < OUTD; ++od) {
        o[od] += __shfl_xor(o[od], 1);
        o[od] += __shfl_xor(o[od], 2);
        o[od] += bs[od];
    }

    if (xf32) {
        float2* po = (float2*)((float*)out + (size_t)node * OUTD);
        if (q == 0) {
            po[0] = make_float2(o[0], o[1]);
            po[1] = make_float2(o[2], o[3]);
        } else if (q == 1) {
            po[2] = make_float2(o[4], o[5]);
            po[3] = make_float2(o[6], o[7]);
        } else if (q == 2) {
            po[4] = make_float2(o[8], o[9]);
        }
    } else {
        unsigned int* po = (unsigned int*)((unsigned short*)out + (size_t)node * OUTD);
        if (q == 0) {
            po[0] = (unsigned int)f2bf(o[0]) | ((unsigned int)f2bf(o[1]) << 16);
            po[1] = (unsigned int)f2bf(o[2]) | ((unsigned int)f2bf(o[3]) << 16);
        } else if (q == 1) {
            po[2] = (unsigned int)f2bf(o[4]) | ((unsigned int)f2bf(o[5]) << 16);
            po[3] = (unsigned int)f2bf(o[6]) | ((unsigned int)f2bf(o[7]) << 16);
        } else if (q == 2) {
            po[4] = (unsigned int)f2bf(o[8]) | ((unsigned int)f2bf(o[9]) << 16);
        }
    }
}

// ---------------- Sentinel: ws_size too small -------------------------------
__global__ void sentinel_kernel(float* __restrict__ out) {
    if (blockIdx.x == 0 && threadIdx.x < 16) out[threadIdx.x] = 123456.0f;
}

extern "C" void kernel_launch(void* const* d_in, const int* in_sizes, int n_in,
                              void* d_out, int out_size, void* d_ws, size_t ws_size,
                              hipStream_t stream) {
    const void* x  = d_in[0];
    const void* ei = d_in[1];
    const void* W1 = d_in[2];
    const void* b1 = d_in[3];
    const void* W2 = d_in[4];
    const void* b2 = d_in[5];

    const int n_nodes = in_sizes[0] / IN_DIM;        // 100000
    const int n_edges = in_sizes[1] / 2;             // 3200000
    const int K = (n_nodes + BKT_W - 1) / BKT_W;     // 391 buckets

    char* p = (char*)d_ws;
    auto align = [](size_t v) { return (v + 255) & ~(size_t)255; };
    size_t off = 0;
    int* flags      = (int*)(p + off); off = align(off + 256);
    unsigned short* w1split = (unsigned short*)(p + off); off = align(off + 8192 * 2);
    int* bucket_cnt = (int*)(p + off); off = align(off + (size_t)K * 4);
    int* bucket_off = (int*)(p + off); off = align(off + ((size_t)K + 1) * 4);
    int* bcur       = (int*)(p + off); off = align(off + (size_t)K * 4);
    int* row_off    = (int*)(p + off); off = align(off + ((size_t)n_nodes + 1) * 4);
    int* csr_src    = (int*)(p + off); off = align(off + (size_t)n_edges * 4);
    unsigned int* pairs = (unsigned int*)(p + off); off = align(off + (size_t)n_edges * 4);
    unsigned short* m1 = (unsigned short*)(p + off); off = align(off + (size_t)n_nodes * HID * 2);
    unsigned short* h  = (unsigned short*)(p + off); off = align(off + (size_t)n_nodes * HID * 2);

    if (ws_size < off) {
        sentinel_kernel<<<1, 64, 0, stream>>>((float*)d_out);
        return;
    }

    const int n_tiles16 = (n_nodes + 15) >> 4;        // 6250
    const int g_gemm = (n_tiles16 + 3) / 4;           // 1563 (1 tile/wave)
    const int g_part = (n_edges + PART_CH - 1) / PART_CH;  // 782

    // 0. zero bucket counters
    zero_kernel<<<1, 256, 0, stream>>>(bucket_cnt, K);

    // 1. K1 fat: flags + W1 split + bucket histogram
    setup_bhist_kernel<<<17 + G_HIST, 256, 0, stream>>>(
        x, W1, ei, n_nodes, n_edges, flags, bucket_cnt, K, w1split);

    // 2. bucket scan
    bscan_kernel<<<1, 256, 0, stream>>>(bucket_cnt, K, bucket_off, bcur,
                                        row_off, n_nodes, n_edges);

    // 3. K2 fat: partition overlapped with gemm1
    part_gemm1_kernel<<<g_part + g_gemm, 256, 0, stream>>>(
        ei, n_edges, bcur, pairs, x, w1split, m1, n_nodes, flags, K, g_part);

    // 4. K3 cooperative: csr + agg1 | grid.sync | agg2 + out
    {
        const unsigned int* pairs_c = pairs;
        const int* bucket_off_c = bucket_off;
        const unsigned short* m1_c = m1;
        const void* b1_c = b1;
        const void* W2_c = W2;
        const void* b2_c = b2;
        int* spill_c = csr_src;
        unsigned short* h_c = h;
        void* out_c = d_out;
        int n_nodes_c = n_nodes;
        const int* flags_c = flags;
        void* args[] = {
            (void*)&pairs_c, (void*)&bucket_off_c, (void*)&m1_c,
            (void*)&b1_c, (void*)&W2_c, (void*)&b2_c,
            (void*)&spill_c, (void*)&h_c, (void*)&out_c,
            (void*)&n_nodes_c, (void*)&flags_c
        };
        hipError_t err = hipLaunchCooperativeKernel(
            (const void*)csr_agg12_kernel, dim3(K), dim3(512), args, 0, stream);
        if (err != hipSuccess) {
            // fallback: proven round-8 two-kernel path
            csr_agg1_kernel<<<K, 512, 0, stream>>>(
                pairs, bucket_off, m1, b1, row_off, csr_src, h, n_nodes, flags);
            long long threads = (long long)n_nodes * 4;
            agg2_out_kernel<<<(int)((threads + 255) / 256), 256, 0, stream>>>(
                h, row_off, csr_src, W2, b2, d_out, n_nodes, flags);
        }
    }
}

// Round 10
// 294.026 us; speedup vs baseline: 1.4755x; 1.4755x over previous
//
#include <hip/hip_runtime.h>
#include <hip/hip_bf16.h>
#include <stdint.h>

#define IN_DIM 256
#define HID 16
#define OUTD 10
#define BKT_SHIFT 8            // 256 nodes per bucket
#define BKT_W 256
#define PART_CH 8192           // edges per partition block (fixed-cost amortize)
#define EPT 16                 // edges per thread in part (PART_CH/512)
#define G_HIST 512             // histogram blocks in K1
#define SSRC_CAP 8704          // csr_agg1 LDS src capacity (mean 8192 + ~5 sigma)

typedef short v8s __attribute__((ext_vector_type(8)));
typedef float v4f __attribute__((ext_vector_type(4)));

__device__ __forceinline__ float bf2f(unsigned short u) {
    return __uint_as_float(((unsigned int)u) << 16);
}
__device__ __forceinline__ unsigned short f2bf(float f) {
    unsigned int u = __float_as_uint(f);
    unsigned int lsb = (u >> 16) & 1u;
    u += 0x7fffu + lsb;  // round-to-nearest-even
    return (unsigned short)(u >> 16);
}

__device__ __forceinline__ int load_dst(const void* ei, int n_edges, int e, int is64) {
    return is64 ? (int)((const long long*)ei)[(size_t)n_edges + e]
                : ((const int*)ei)[(size_t)n_edges + e];
}
__device__ __forceinline__ int load_src(const void* ei, int n_edges, int e, int is64) {
    return is64 ? (int)((const long long*)ei)[e] : ((const int*)ei)[e];
}

// ---------------- zero: bucket counters (plain kernel, no memset API) -------
__global__ void zero_kernel(int* __restrict__ bucket_cnt, int K) {
    for (int i = threadIdx.x; i < K; i += blockDim.x) bucket_cnt[i] = 0;
}

// ---------------- K1 fat: setup/flags/W1-split (17 blocks) + bhist ----------
__global__ void setup_bhist_kernel(const void* __restrict__ x,
                                   const void* __restrict__ W1,
                                   const void* __restrict__ ei,
                                   int n_nodes, int n_edges,
                                   int* __restrict__ flags,
                                   int* __restrict__ bucket_cnt, int K,
                                   unsigned short* __restrict__ W1split) {
    __shared__ int lh[512];
    __shared__ int sflag;
    int b = blockIdx.x, t = threadIdx.x;

    if (b < 16) {
        // ---- W1 split role (local wf32 detect over first 256 values) ----
        if (t == 0) sflag = 0;
        __syncthreads();
        {
            float vw = bf2f(((const unsigned short*)W1)[t]);
            if (!(vw > -1e4f && vw < 1e4f)) sflag = 1;   // benign same-value race
        }
        __syncthreads();
        const int wf32 = sflag;
        int i = b * 256 + t;                       // 0..4095 (i = k*16 + n)
        float w = wf32 ? ((const float*)W1)[i]
                       : bf2f(((const unsigned short*)W1)[i]);
        unsigned short hi = f2bf(w);
        unsigned short lo = f2bf(w - bf2f(hi));
        int k = i >> 4, n = i & 15;
        int kk = k >> 5, qd = (k >> 3) & 3, j = k & 7;
        int idx = ((kk * 4 + qd) * 16 + n) * 8 + j;  // = (kk*64 + lane)*8 + j
        W1split[idx] = hi;
        W1split[4096 + idx] = lo;
        return;
    }
    if (b == 16) {
        // ---- global flags role ----
        if (t < 64) {
            const unsigned short* xs = (const unsigned short*)x;
            const unsigned short* ws = (const unsigned short*)W1;
            bool badx = false, badw = false;
#pragma unroll
            for (int q = 0; q < 4; ++q) {
                float vx = bf2f(xs[t + 64 * q]);
                float vw = bf2f(ws[t + 64 * q]);
                if (!(vx > -1e4f && vx < 1e4f)) badx = true;
                if (!(vw > -1e4f && vw < 1e4f)) badw = true;
            }
            const unsigned long long* e64 = (const unsigned long long*)ei;
            bool big = false;
#pragma unroll
            for (int q = 0; q < 2; ++q)
                if (e64[t + 64 * q] >= (unsigned long long)n_nodes) big = true;
            int xf32 = __any(badx) ? 1 : 0;
            int wf32 = __any(badw) ? 1 : 0;
            int is64 = __any(big) ? 0 : 1;
            if (t == 0) { flags[0] = is64; flags[1] = xf32; flags[2] = wf32; }
        }
        return;
    }

    // ---- bhist role (local is64 detect over first 128 u64 reads) ----
    if (t == 0) sflag = 1;
    __syncthreads();
    {
        const unsigned long long* e64 = (const unsigned long long*)ei;
        if (t < 128 && e64[t] >= (unsigned long long)n_nodes) sflag = 0;
    }
    __syncthreads();
    const int is64 = sflag;
    for (int i = t; i < 512; i += 256) lh[i] = 0;
    __syncthreads();
    int vbid = b - 17;
    int stride = G_HIST * 256;
    for (int e = vbid * 256 + t; e < n_edges; e += stride) {
        int d = load_dst(ei, n_edges, e, is64);
        atomicAdd(&lh[d >> BKT_SHIFT], 1);
    }
    __syncthreads();
    for (int i = t; i < K; i += 256)
        if (lh[i]) atomicAdd(&bucket_cnt[i], lh[i]);
}

// ---------------- bucket scan (1 block) -------------------------------------
__global__ void bscan_kernel(const int* __restrict__ bucket_cnt, int K,
                             int* __restrict__ bucket_off, int* __restrict__ bcur,
                             int* __restrict__ row_off, int n_nodes, int n_edges) {
    __shared__ int ts[256];
    int t = threadIdx.x;
    const int KP = (K + 255) / 256;   // <= 8
    int base = t * KP;
    int local[8];
    int s = 0;
    for (int q = 0; q < KP; ++q) {
        int idx = base + q;
        int v = (idx < K) ? bucket_cnt[idx] : 0;
        local[q] = v; s += v;
    }
    ts[t] = s;
    __syncthreads();
    for (int off = 1; off < 256; off <<= 1) {
        int v = (t >= off) ? ts[t - off] : 0;
        __syncthreads();
        ts[t] += v;
        __syncthreads();
    }
    int ex = ts[t] - s;
    for (int q = 0; q < KP; ++q) {
        int idx = base + q;
        if (idx < K) { bucket_off[idx] = ex; bcur[idx] = ex; }
        ex += local[q];
    }
    if (t == 255) bucket_off[K] = ex;
    if (t == 0) row_off[n_nodes] = n_edges;
}

// ---------------- K2 fat: part (blocks < g_part, 512thr) + gemm1 ------------
// part: in-LDS counting sort, PART_CH=8192 (round-6 lesson inverted: part is
// per-block-fixed-cost bound, so fewer/bigger blocks amortize the 512-bucket
// scan + ~390 global reservations + flush). LDS 52KB -> 3 blocks/CU.
// gemm1: m1 = bf16(x @ W1), LDS-free streaming, 8 waves/block.
__global__ __launch_bounds__(512, 4) void part_gemm1_kernel(
        const void* __restrict__ ei, int n_edges,
        int* __restrict__ bcur, unsigned int* __restrict__ pairs,
        const void* __restrict__ xp_,
        const unsigned short* __restrict__ W1split,
        unsigned short* __restrict__ m1, int n_nodes,
        const int* __restrict__ flags, int K, int g_part) {
    __shared__ int lh[512];                  // counts -> in-place scan -> cursor
    __shared__ int gdelta[512];              // gstart[b] - lstart[b]
    __shared__ unsigned int spairs[PART_CH]; // 32 KiB
    __shared__ unsigned short sbkt[PART_CH]; // 16 KiB
    int t = threadIdx.x;

    if ((int)blockIdx.x < g_part) {
        // ---------- partition role (512 threads, 1 bucket-entry each) ----------
        int begin = blockIdx.x * PART_CH;
        int is64 = flags[0];
        lh[t] = 0;

        int dloc[EPT];
#pragma unroll
        for (int i = 0; i < EPT; ++i) {
            int e = begin + i * 512 + t;
            dloc[i] = (e < n_edges) ? load_dst(ei, n_edges, e, is64) : -1;
        }
        __syncthreads();
#pragma unroll
        for (int i = 0; i < EPT; ++i)
            if (dloc[i] >= 0) atomicAdd(&lh[dloc[i] >> BKT_SHIFT], 1);
        __syncthreads();

        // in-place Hillis-Steele inclusive scan of lh[512] (c kept in register)
        int c = lh[t];
        for (int off = 1; off < 512; off <<= 1) {
            int add = (t >= off) ? lh[t - off] : 0;
            __syncthreads();
            lh[t] += add;
            __syncthreads();
        }
        int ex = lh[t] - c;
        if (c > 0) gdelta[t] = atomicAdd(&bcur[t], c) - ex;
        lh[t] = ex;             // own-slot overwrite -> becomes placement cursor
        __syncthreads();        // publishes gdelta + cursors

        // place into LDS, sorted by bucket
#pragma unroll
        for (int i = 0; i < EPT; ++i) {
            int e = begin + i * 512 + t;
            if (dloc[i] >= 0) {
                int srcv = load_src(ei, n_edges, e, is64);
                int bb = dloc[i] >> BKT_SHIFT;
                int lpos = atomicAdd(&lh[bb], 1);
                spairs[lpos] = ((unsigned)srcv << 8) | ((unsigned)dloc[i] & (BKT_W - 1));
                sbkt[lpos] = (unsigned short)bb;
            }
        }
        __syncthreads();

        // coalesced flush: ascending j walks bucket runs contiguously
        int total = n_edges - begin; if (total > PART_CH) total = PART_CH;
        for (int j = t; j < total; j += 512)
            pairs[gdelta[sbkt[j]] + j] = spairs[j];
        return;
    }

    // ---------- gemm1 role (8 waves/block) ----------
    const int xf32 = flags[1];
    int vb = blockIdx.x - g_part;
    int g_gemm = gridDim.x - g_part;
    int lane = t & 63;
    int wave = t >> 6;                 // 0..7
    int col  = lane & 15;
    int quad = lane >> 4;
    int n_tiles = (n_nodes + 15) >> 4;
    const unsigned short* Whi = W1split;
    const unsigned short* Wlo = W1split + 4096;

    if (!xf32) {
        const unsigned short* x = (const unsigned short*)xp_;
        for (int tile = vb * 8 + wave; tile < n_tiles; tile += g_gemm * 8) {
            int row = tile * 16 + col;
            int r = row < n_nodes ? row : n_nodes - 1;
            const unsigned short* xp = x + (size_t)r * IN_DIM + quad * 8;
            v8s a[8];
#pragma unroll
            for (int kk = 0; kk < 8; ++kk)
                a[kk] = *(const v8s*)(xp + kk * 32);
            v4f acc1 = {0.f, 0.f, 0.f, 0.f};
            v4f acc2 = {0.f, 0.f, 0.f, 0.f};
#pragma unroll
            for (int kk = 0; kk < 8; ++kk) {
                v8s bh = *(const v8s*)&Whi[(kk * 64 + lane) * 8];
                v8s bl = *(const v8s*)&Wlo[(kk * 64 + lane) * 8];
                acc1 = __builtin_amdgcn_mfma_f32_16x16x32_bf16(a[kk], bh, acc1, 0, 0, 0);
                acc2 = __builtin_amdgcn_mfma_f32_16x16x32_bf16(a[kk], bl, acc2, 0, 0, 0);
            }
#pragma unroll
            for (int rg = 0; rg < 4; ++rg) {
                int node = tile * 16 + quad * 4 + rg;
                if (node < n_nodes)
                    m1[(size_t)node * HID + col] = f2bf(acc1[rg] + acc2[rg]);
            }
        }
    } else {
        const float* x = (const float*)xp_;
        for (int tile = vb * 8 + wave; tile < n_tiles; tile += g_gemm * 8) {
            int row = tile * 16 + col;
            int r = row < n_nodes ? row : n_nodes - 1;
            const float* xp = x + (size_t)r * IN_DIM + quad * 8;
            float4 u[16];
#pragma unroll
            for (int kk = 0; kk < 8; ++kk) {
                u[2 * kk]     = *(const float4*)(xp + kk * 32);
                u[2 * kk + 1] = *(const float4*)(xp + kk * 32 + 4);
            }
            v4f acc1 = {0.f, 0.f, 0.f, 0.f};   // ahi*bh chain
            v4f acc2 = {0.f, 0.f, 0.f, 0.f};   // ahi*bl + alo*bh chain
#pragma unroll
            for (int kk = 0; kk < 8; ++kk) {
                float uv[8] = {u[2 * kk].x,     u[2 * kk].y,
                               u[2 * kk].z,     u[2 * kk].w,
                               u[2 * kk + 1].x, u[2 * kk + 1].y,
                               u[2 * kk + 1].z, u[2 * kk + 1].w};
                v8s ahi, alo;
#pragma unroll
                for (int j = 0; j < 8; ++j) {
                    unsigned short hi = f2bf(uv[j]);
                    unsigned short lo = f2bf(uv[j] - bf2f(hi));
                    ahi[j] = (short)hi; alo[j] = (short)lo;
                }
                v8s bh = *(const v8s*)&Whi[(kk * 64 + lane) * 8];
                v8s bl = *(const v8s*)&Wlo[(kk * 64 + lane) * 8];
                acc1 = __builtin_amdgcn_mfma_f32_16x16x32_bf16(ahi, bh, acc1, 0, 0, 0);
                acc2 = __builtin_amdgcn_mfma_f32_16x16x32_bf16(ahi, bl, acc2, 0, 0, 0);
                acc2 = __builtin_amdgcn_mfma_f32_16x16x32_bf16(alo, bh, acc2, 0, 0, 0);
            }
#pragma unroll
            for (int rg = 0; rg < 4; ++rg) {
                int node = tile * 16 + quad * 4 + rg;
                if (node < n_nodes)
                    m1[(size_t)node * HID + col] = f2bf(acc1[rg] + acc2[rg]);
            }
        }
    }
}

// ---------------- K3: csr build + agg1 fused (one block per bucket) ---------
__global__ __launch_bounds__(512) void csr_agg1_kernel(
        const unsigned int* __restrict__ pairs,
        const int* __restrict__ bucket_off,
        const unsigned short* __restrict__ m1,
        const void* __restrict__ b1p,
        int* __restrict__ row_off, int* __restrict__ csr_src,
        unsigned short* __restrict__ h,
        int n_nodes, const int* __restrict__ flags) {
    __shared__ unsigned int ssrc[SSRC_CAP];   // 34 KiB sorted src list
    __shared__ int deg[BKT_W];
    __shared__ int cur[BKT_W];
    __shared__ int ts[BKT_W];
    int blk = blockIdx.x;
    int nbase = blk << BKT_SHIFT;
    int NL = n_nodes - nbase; if (NL > BKT_W) NL = BKT_W;
    int beg = bucket_off[blk], end = bucket_off[blk + 1];
    int t = threadIdx.x;

    if (t < BKT_W) deg[t] = 0;
    __syncthreads();
    for (int k = beg + t; k < end; k += 512)
        atomicAdd(&deg[pairs[k] & (BKT_W - 1)], 1);
    __syncthreads();
    if (t < BKT_W) ts[t] = deg[t];
    __syncthreads();
    for (int off = 1; off < BKT_W; off <<= 1) {
        int v = 0;
        if (t < BKT_W && t >= off) v = ts[t - off];
        __syncthreads();
        if (t < BKT_W) ts[t] += v;
        __syncthreads();
    }
    if (t < BKT_W) {
        int exl = ts[t] - deg[t];
        cur[t] = exl;
        if (t < NL) row_off[nbase + t] = beg + exl;
    }
    __syncthreads();
    // placement: global csr_src (for agg2) + LDS copy (for the fused agg1)
    for (int k = beg + t; k < end; k += 512) {
        unsigned int pr = pairs[k];
        int dl = pr & (BKT_W - 1);
        int pos = atomicAdd(&cur[dl], 1);
        int src = (int)(pr >> 8);
        csr_src[beg + pos] = src;
        if (pos < SSRC_CAP) ssrc[pos] = (unsigned)src;
    }
    __syncthreads();

    // ---- fused agg1: 4 lanes per node, 128 node-groups, 2 passes ----
    const int wf32 = flags[2];
    int q = t & 3, grp = t >> 2;
    float b0, b1v, b2v, b3;
    if (wf32) {
        const float* b = (const float*)b1p + q * 4;
        b0 = b[0]; b1v = b[1]; b2v = b[2]; b3 = b[3];
    } else {
        const unsigned short* b = (const unsigned short*)b1p + q * 4;
        b0 = bf2f(b[0]); b1v = bf2f(b[1]); b2v = bf2f(b[2]); b3 = bf2f(b[3]);
    }
    for (int nl = grp; nl < NL; nl += 128) {
        int sL = ts[nl] - deg[nl];
        int eL = ts[nl];
        float a0 = 0.f, a1 = 0.f, a2 = 0.f, a3 = 0.f;
        int k = sL;
        for (; k + 8 <= eL; k += 8) {
            int sidx[8];
            uint2 v[8];
#pragma unroll
            for (int u = 0; u < 8; ++u)
                sidx[u] = (k + u < SSRC_CAP) ? (int)ssrc[k + u]
                                             : csr_src[beg + k + u];
#pragma unroll
            for (int u = 0; u < 8; ++u)
                v[u] = *(const uint2*)(m1 + (size_t)sidx[u] * HID + q * 4);
#pragma unroll
            for (int u = 0; u < 8; ++u) {
                a0 += bf2f((unsigned short)(v[u].x));
                a1 += bf2f((unsigned short)(v[u].x >> 16));
                a2 += bf2f((unsigned short)(v[u].y));
                a3 += bf2f((unsigned short)(v[u].y >> 16));
            }
        }
        for (; k < eL; ++k) {
            int s = (k < SSRC_CAP) ? (int)ssrc[k] : csr_src[beg + k];
            uint2 v = *(const uint2*)(m1 + (size_t)s * HID + q * 4);
            a0 += bf2f((unsigned short)(v.x));
            a1 += bf2f((unsigned short)(v.x >> 16));
            a2 += bf2f((unsigned short)(v.y));
            a3 += bf2f((unsigned short)(v.y >> 16));
        }
        float r0 = fmaxf(a0 + b0, 0.f);
        float r1 = fmaxf(a1 + b1v, 0.f);
        float r2 = fmaxf(a2 + b2v, 0.f);
        float r3 = fmaxf(a3 + b3, 0.f);
        uint2 packed;
        packed.x = (unsigned int)f2bf(r0) | ((unsigned int)f2bf(r1) << 16);
        packed.y = (unsigned int)f2bf(r2) | ((unsigned int)f2bf(r3) << 16);
        *(uint2*)(h + (size_t)(nbase + nl) * HID + q * 4) = packed;
    }
}

// ---------------- gather-sum core: 4 lanes/node, bf16 rows, 16-deep MLP -----
__device__ __forceinline__ v4f gather_bf16(const unsigned short* __restrict__ src,
                                           const int* __restrict__ csr_src,
                                           int beg, int end, int q) {
    float a0 = 0.f, a1 = 0.f, a2 = 0.f, a3 = 0.f;
    int k = beg;
    for (; k + 16 <= end; k += 16) {
        uint2 v[16];
#pragma unroll
        for (int u = 0; u < 16; ++u) {
            int s = csr_src[k + u];
            v[u] = *(const uint2*)(src + (size_t)s * HID + q * 4);
        }
#pragma unroll
        for (int u = 0; u < 16; ++u) {
            a0 += bf2f((unsigned short)(v[u].x));
            a1 += bf2f((unsigned short)(v[u].x >> 16));
            a2 += bf2f((unsigned short)(v[u].y));
            a3 += bf2f((unsigned short)(v[u].y >> 16));
        }
    }
    for (; k + 4 <= end; k += 4) {
        uint2 v[4];
#pragma unroll
        for (int u = 0; u < 4; ++u) {
            int s = csr_src[k + u];
            v[u] = *(const uint2*)(src + (size_t)s * HID + q * 4);
        }
#pragma unroll
        for (int u = 0; u < 4; ++u) {
            a0 += bf2f((unsigned short)(v[u].x));
            a1 += bf2f((unsigned short)(v[u].x >> 16));
            a2 += bf2f((unsigned short)(v[u].y));
            a3 += bf2f((unsigned short)(v[u].y >> 16));
        }
    }
    for (; k < end; ++k) {
        int s = csr_src[k];
        uint2 v = *(const uint2*)(src + (size_t)s * HID + q * 4);
        a0 += bf2f((unsigned short)(v.x));
        a1 += bf2f((unsigned short)(v.x >> 16));
        a2 += bf2f((unsigned short)(v.y));
        a3 += bf2f((unsigned short)(v.y >> 16));
    }
    v4f r = {a0, a1, a2, a3};
    return r;
}

// ---------------- agg2 + out fused: out = (A . h) @ W2 + b2 -----------------
__global__ void agg2_out_kernel(const unsigned short* __restrict__ h,
                                const int* __restrict__ row_off,
                                const int* __restrict__ csr_src,
                                const void* __restrict__ W2p,
                                const void* __restrict__ b2p,
                                void* __restrict__ out, int n_nodes,
                                const int* __restrict__ flags) {
    __shared__ float Ws[HID * OUTD];
    __shared__ float bs[OUTD];
    const int xf32 = flags[1], wf32 = flags[2];
    if (threadIdx.x < HID * OUTD)
        Ws[threadIdx.x] = wf32 ? ((const float*)W2p)[threadIdx.x]
                               : bf2f(((const unsigned short*)W2p)[threadIdx.x]);
    if (threadIdx.x < OUTD)
        bs[threadIdx.x] = wf32 ? ((const float*)b2p)[threadIdx.x]
                               : bf2f(((const unsigned short*)b2p)[threadIdx.x]);
    __syncthreads();

    int t = blockIdx.x * blockDim.x + threadIdx.x;
    int node = t >> 2;
    if (node >= n_nodes) return;
    int q = t & 3;
    v4f a = gather_bf16(h, csr_src, row_off[node], row_off[node + 1], q);

    float o[OUTD];
#pragma unroll
    for (int od = 0; od < OUTD; ++od) {
        float s = 0.f;
#pragma unroll
        for (int j = 0; j < 4; ++j)
            s = fmaf(a[j], Ws[(q * 4 + j) * OUTD + od], s);
        o[od] = s;
    }
#pragma unroll
    for (int od = 0; od < OUTD; ++od) {
        o[od] += __shfl_xor(o[od], 1);
        o[od] += __shfl_xor(o[od], 2);
        o[od] += bs[od];
    }

    if (xf32) {
        float2* po = (float2*)((float*)out + (size_t)node * OUTD);
        if (q == 0) {
            po[0] = make_float2(o[0], o[1]);
            po[1] = make_float2(o[2], o[3]);
        } else if (q == 1) {
            po[2] = make_float2(o[4], o[5]);
            po[3] = make_float2(o[6], o[7]);
        } else if (q == 2) {
            po[4] = make_float2(o[8], o[9]);
        }
    } else {
        unsigned int* po = (unsigned int*)((unsigned short*)out + (size_t)node * OUTD);
        if (q == 0) {
            po[0] = (unsigned int)f2bf(o[0]) | ((unsigned int)f2bf(o[1]) << 16);
            po[1] = (unsigned int)f2bf(o[2]) | ((unsigned int)f2bf(o[3]) << 16);
        } else if (q == 1) {
            po[2] = (unsigned int)f2bf(o[4]) | ((unsigned int)f2bf(o[5]) << 16);
            po[3] = (unsigned int)f2bf(o[6]) | ((unsigned int)f2bf(o[7]) << 16);
        } else if (q == 2) {
            po[4] = (unsigned int)f2bf(o[8]) | ((unsigned int)f2bf(o[9]) << 16);
        }
    }
}

// ---------------- Sentinel: ws_size too small -------------------------------
__global__ void sentinel_kernel(float* __restrict__ out) {
    if (blockIdx.x == 0 && threadIdx.x < 16) out[threadIdx.x] = 123456.0f;
}

extern "C" void kernel_launch(void* const* d_in, const int* in_sizes, int n_in,
                              void* d_out, int out_size, void* d_ws, size_t ws_size,
                              hipStream_t stream) {
    const void* x  = d_in[0];
    const void* ei = d_in[1];
    const void* W1 = d_in[2];
    const void* b1 = d_in[3];
    const void* W2 = d_in[4];
    const void* b2 = d_in[5];

    const int n_nodes = in_sizes[0] / IN_DIM;        // 100000
    const int n_edges = in_sizes[1] / 2;             // 3200000
    const int K = (n_nodes + BKT_W - 1) / BKT_W;     // 391 buckets

    // Workspace layout (256B-aligned). gemm1 overlaps part -> m1/h do not
    // alias pairs.
    char* p = (char*)d_ws;
    auto align = [](size_t v) { return (v + 255) & ~(size_t)255; };
    size_t off = 0;
    int* flags      = (int*)(p + off); off = align(off + 256);
    unsigned short* w1split = (unsigned short*)(p + off); off = align(off + 8192 * 2);
    int* bucket_cnt = (int*)(p + off); off = align(off + (size_t)K * 4);
    int* bucket_off = (int*)(p + off); off = align(off + ((size_t)K + 1) * 4);
    int* bcur       = (int*)(p + off); off = align(off + (size_t)K * 4);
    int* row_off    = (int*)(p + off); off = align(off + ((size_t)n_nodes + 1) * 4);
    int* csr_src    = (int*)(p + off); off = align(off + (size_t)n_edges * 4);
    unsigned int* pairs = (unsigned int*)(p + off); off = align(off + (size_t)n_edges * 4);
    unsigned short* m1 = (unsigned short*)(p + off); off = align(off + (size_t)n_nodes * HID * 2);
    unsigned short* h  = (unsigned short*)(p + off); off = align(off + (size_t)n_nodes * HID * 2);

    if (ws_size < off) {
        sentinel_kernel<<<1, 64, 0, stream>>>((float*)d_out);
        return;
    }

    const int n_tiles16 = (n_nodes + 15) >> 4;        // 6250
    const int g_gemm = (n_tiles16 + 7) / 8;           // 782 (1 tile/wave, 8 waves)
    const int g_part = (n_edges + PART_CH - 1) / PART_CH;  // 391

    // 0. zero bucket counters
    zero_kernel<<<1, 256, 0, stream>>>(bucket_cnt, K);

    // 1. K1 fat: flags + W1 split + bucket histogram
    setup_bhist_kernel<<<17 + G_HIST, 256, 0, stream>>>(
        x, W1, ei, n_nodes, n_edges, flags, bucket_cnt, K, w1split);

    // 2. bucket scan
    bscan_kernel<<<1, 256, 0, stream>>>(bucket_cnt, K, bucket_off, bcur,
                                        row_off, n_nodes, n_edges);

    // 3. K2 fat: partition overlapped with gemm1 (512-thread blocks)
    part_gemm1_kernel<<<g_part + g_gemm, 512, 0, stream>>>(
        ei, n_edges, bcur, pairs, x, w1split, m1, n_nodes, flags, K, g_part);

    // 4. K3: per-bucket CSR build + layer-1 aggregation fused
    csr_agg1_kernel<<<K, 512, 0, stream>>>(pairs, bucket_off, m1, b1,
                                           row_off, csr_src, h, n_nodes, flags);

    // 5. layer 2 aggregation + output GEMM fused
    {
        long long threads = (long long)n_nodes * 4;
        agg2_out_kernel<<<(int)((threads + 255) / 256), 256, 0, stream>>>(
            h, row_off, csr_src, W2, b2, d_out, n_nodes, flags);
    }
}

// Round 11
// 289.942 us; speedup vs baseline: 1.4963x; 1.0141x over previous
//
#include <hip/hip_runtime.h>
#include <hip/hip_bf16.h>
#include <stdint.h>

#define IN_DIM 256
#define HID 16
#define OUTD 10
#define BKT_SHIFT 8            // 256 nodes per bucket
#define BKT_W 256
#define PART_CH 8192           // edges per partition block (fixed-cost amortize)
#define EPT 16                 // edges per thread in part (PART_CH/512)
#define G_HIST 512             // histogram blocks in K1
#define SSRC_CAP 8704          // csr_agg1 LDS src capacity (mean 8192 + ~5 sigma)

typedef short v8s __attribute__((ext_vector_type(8)));
typedef float v4f __attribute__((ext_vector_type(4)));

__device__ __forceinline__ float bf2f(unsigned short u) {
    return __uint_as_float(((unsigned int)u) << 16);
}
__device__ __forceinline__ unsigned short f2bf(float f) {
    unsigned int u = __float_as_uint(f);
    unsigned int lsb = (u >> 16) & 1u;
    u += 0x7fffu + lsb;  // round-to-nearest-even
    return (unsigned short)(u >> 16);
}

// split a float pair into packed-bf16 (hi,lo) via v_perm_b32: 6 ops / 2 elems.
// hi = truncated top-16 bits (exact bf16); lo = bf16_trunc(x - hi) captures
// the remainder -> hi+lo keeps ~2^-16 relative accuracy (fp32-grade for the
// 3-MFMA split product). Replaces ~9 ops/elem RNE path (K2 was VALU-bound
// on conversion: 600 VALU inst vs 24 MFMA per tile).
__device__ __forceinline__ void split2(float f0, float f1,
                                       unsigned int& hi2, unsigned int& lo2) {
    unsigned int u0 = __float_as_uint(f0);
    unsigned int u1 = __float_as_uint(f1);
    hi2 = __builtin_amdgcn_perm(u1, u0, 0x07060302u);   // [u0.hi16, u1.hi16]
    float h0 = __uint_as_float(u0 & 0xFFFF0000u);
    float h1 = __uint_as_float(u1 & 0xFFFF0000u);
    unsigned int l0 = __float_as_uint(f0 - h0);
    unsigned int l1 = __float_as_uint(f1 - h1);
    lo2 = __builtin_amdgcn_perm(l1, l0, 0x07060302u);
}

__device__ __forceinline__ int load_dst(const void* ei, int n_edges, int e, int is64) {
    return is64 ? (int)((const long long*)ei)[(size_t)n_edges + e]
                : ((const int*)ei)[(size_t)n_edges + e];
}
__device__ __forceinline__ int load_src(const void* ei, int n_edges, int e, int is64) {
    return is64 ? (int)((const long long*)ei)[e] : ((const int*)ei)[e];
}

// ---------------- zero: bucket counters (plain kernel, no memset API) -------
__global__ void zero_kernel(int* __restrict__ bucket_cnt, int K) {
    for (int i = threadIdx.x; i < K; i += blockDim.x) bucket_cnt[i] = 0;
}

// ---------------- K1 fat: setup/flags/W1-split (17 blocks) + bhist ----------
__global__ void setup_bhist_kernel(const void* __restrict__ x,
                                   const void* __restrict__ W1,
                                   const void* __restrict__ ei,
                                   int n_nodes, int n_edges,
                                   int* __restrict__ flags,
                                   int* __restrict__ bucket_cnt, int K,
                                   unsigned short* __restrict__ W1split) {
    __shared__ int lh[512];
    __shared__ int sflag;
    int b = blockIdx.x, t = threadIdx.x;

    if (b < 16) {
        // ---- W1 split role (local wf32 detect over first 256 values) ----
        if (t == 0) sflag = 0;
        __syncthreads();
        {
            float vw = bf2f(((const unsigned short*)W1)[t]);
            if (!(vw > -1e4f && vw < 1e4f)) sflag = 1;   // benign same-value race
        }
        __syncthreads();
        const int wf32 = sflag;
        int i = b * 256 + t;                       // 0..4095 (i = k*16 + n)
        float w = wf32 ? ((const float*)W1)[i]
                       : bf2f(((const unsigned short*)W1)[i]);
        unsigned short hi = f2bf(w);
        unsigned short lo = f2bf(w - bf2f(hi));
        int k = i >> 4, n = i & 15;
        int kk = k >> 5, qd = (k >> 3) & 3, j = k & 7;
        int idx = ((kk * 4 + qd) * 16 + n) * 8 + j;  // = (kk*64 + lane)*8 + j
        W1split[idx] = hi;
        W1split[4096 + idx] = lo;
        return;
    }
    if (b == 16) {
        // ---- global flags role ----
        if (t < 64) {
            const unsigned short* xs = (const unsigned short*)x;
            const unsigned short* ws = (const unsigned short*)W1;
            bool badx = false, badw = false;
#pragma unroll
            for (int q = 0; q < 4; ++q) {
                float vx = bf2f(xs[t + 64 * q]);
                float vw = bf2f(ws[t + 64 * q]);
                if (!(vx > -1e4f && vx < 1e4f)) badx = true;
                if (!(vw > -1e4f && vw < 1e4f)) badw = true;
            }
            const unsigned long long* e64 = (const unsigned long long*)ei;
            bool big = false;
#pragma unroll
            for (int q = 0; q < 2; ++q)
                if (e64[t + 64 * q] >= (unsigned long long)n_nodes) big = true;
            int xf32 = __any(badx) ? 1 : 0;
            int wf32 = __any(badw) ? 1 : 0;
            int is64 = __any(big) ? 0 : 1;
            if (t == 0) { flags[0] = is64; flags[1] = xf32; flags[2] = wf32; }
        }
        return;
    }

    // ---- bhist role (local is64 detect over first 128 u64 reads) ----
    if (t == 0) sflag = 1;
    __syncthreads();
    {
        const unsigned long long* e64 = (const unsigned long long*)ei;
        if (t < 128 && e64[t] >= (unsigned long long)n_nodes) sflag = 0;
    }
    __syncthreads();
    const int is64 = sflag;
    for (int i = t; i < 512; i += 256) lh[i] = 0;
    __syncthreads();
    int vbid = b - 17;
    int stride = G_HIST * 256;
    for (int e = vbid * 256 + t; e < n_edges; e += stride) {
        int d = load_dst(ei, n_edges, e, is64);
        atomicAdd(&lh[d >> BKT_SHIFT], 1);
    }
    __syncthreads();
    for (int i = t; i < K; i += 256)
        if (lh[i]) atomicAdd(&bucket_cnt[i], lh[i]);
}

// ---------------- bucket scan (1 block) -------------------------------------
__global__ void bscan_kernel(const int* __restrict__ bucket_cnt, int K,
                             int* __restrict__ bucket_off, int* __restrict__ bcur,
                             int* __restrict__ row_off, int n_nodes, int n_edges) {
    __shared__ int ts[256];
    int t = threadIdx.x;
    const int KP = (K + 255) / 256;   // <= 8
    int base = t * KP;
    int local[8];
    int s = 0;
    for (int q = 0; q < KP; ++q) {
        int idx = base + q;
        int v = (idx < K) ? bucket_cnt[idx] : 0;
        local[q] = v; s += v;
    }
    ts[t] = s;
    __syncthreads();
    for (int off = 1; off < 256; off <<= 1) {
        int v = (t >= off) ? ts[t - off] : 0;
        __syncthreads();
        ts[t] += v;
        __syncthreads();
    }
    int ex = ts[t] - s;
    for (int q = 0; q < KP; ++q) {
        int idx = base + q;
        if (idx < K) { bucket_off[idx] = ex; bcur[idx] = ex; }
        ex += local[q];
    }
    if (t == 255) bucket_off[K] = ex;
    if (t == 0) row_off[n_nodes] = n_edges;
}

// ---------------- K2 fat: part (blocks < g_part, 512thr) + gemm1 ------------
// part: in-LDS counting sort, PART_CH=8192 (proven round 10).
// gemm1: m1 = bf16(x @ W1), LDS-free streaming, 8 waves/block; fp32 path uses
// perm-packed truncated split (3 ops/elem vs ~9 -> gemm VALU / 3).
__global__ __launch_bounds__(512, 4) void part_gemm1_kernel(
        const void* __restrict__ ei, int n_edges,
        int* __restrict__ bcur, unsigned int* __restrict__ pairs,
        const void* __restrict__ xp_,
        const unsigned short* __restrict__ W1split,
        unsigned short* __restrict__ m1, int n_nodes,
        const int* __restrict__ flags, int K, int g_part) {
    __shared__ int lh[512];                  // counts -> in-place scan -> cursor
    __shared__ int gdelta[512];              // gstart[b] - lstart[b]
    __shared__ unsigned int spairs[PART_CH]; // 32 KiB
    __shared__ unsigned short sbkt[PART_CH]; // 16 KiB
    int t = threadIdx.x;

    if ((int)blockIdx.x < g_part) {
        // ---------- partition role (512 threads, 1 bucket-entry each) ----------
        int begin = blockIdx.x * PART_CH;
        int is64 = flags[0];
        lh[t] = 0;

        int dloc[EPT];
#pragma unroll
        for (int i = 0; i < EPT; ++i) {
            int e = begin + i * 512 + t;
            dloc[i] = (e < n_edges) ? load_dst(ei, n_edges, e, is64) : -1;
        }
        __syncthreads();
#pragma unroll
        for (int i = 0; i < EPT; ++i)
            if (dloc[i] >= 0) atomicAdd(&lh[dloc[i] >> BKT_SHIFT], 1);
        __syncthreads();

        // in-place Hillis-Steele inclusive scan of lh[512] (c kept in register)
        int c = lh[t];
        for (int off = 1; off < 512; off <<= 1) {
            int add = (t >= off) ? lh[t - off] : 0;
            __syncthreads();
            lh[t] += add;
            __syncthreads();
        }
        int ex = lh[t] - c;
        if (c > 0) gdelta[t] = atomicAdd(&bcur[t], c) - ex;
        lh[t] = ex;             // own-slot overwrite -> becomes placement cursor
        __syncthreads();        // publishes gdelta + cursors

        // place into LDS, sorted by bucket
#pragma unroll
        for (int i = 0; i < EPT; ++i) {
            int e = begin + i * 512 + t;
            if (dloc[i] >= 0) {
                int srcv = load_src(ei, n_edges, e, is64);
                int bb = dloc[i] >> BKT_SHIFT;
                int lpos = atomicAdd(&lh[bb], 1);
                spairs[lpos] = ((unsigned)srcv << 8) | ((unsigned)dloc[i] & (BKT_W - 1));
                sbkt[lpos] = (unsigned short)bb;
            }
        }
        __syncthreads();

        // coalesced flush: ascending j walks bucket runs contiguously
        int total = n_edges - begin; if (total > PART_CH) total = PART_CH;
        for (int j = t; j < total; j += 512)
            pairs[gdelta[sbkt[j]] + j] = spairs[j];
        return;
    }

    // ---------- gemm1 role (8 waves/block) ----------
    const int xf32 = flags[1];
    int vb = blockIdx.x - g_part;
    int g_gemm = gridDim.x - g_part;
    int lane = t & 63;
    int wave = t >> 6;                 // 0..7
    int col  = lane & 15;
    int quad = lane >> 4;
    int n_tiles = (n_nodes + 15) >> 4;
    const unsigned short* Whi = W1split;
    const unsigned short* Wlo = W1split + 4096;

    if (!xf32) {
        const unsigned short* x = (const unsigned short*)xp_;
        for (int tile = vb * 8 + wave; tile < n_tiles; tile += g_gemm * 8) {
            int row = tile * 16 + col;
            int r = row < n_nodes ? row : n_nodes - 1;
            const unsigned short* xp = x + (size_t)r * IN_DIM + quad * 8;
            v8s a[8];
#pragma unroll
            for (int kk = 0; kk < 8; ++kk)
                a[kk] = *(const v8s*)(xp + kk * 32);
            v4f acc1 = {0.f, 0.f, 0.f, 0.f};
            v4f acc2 = {0.f, 0.f, 0.f, 0.f};
#pragma unroll
            for (int kk = 0; kk < 8; ++kk) {
                v8s bh = *(const v8s*)&Whi[(kk * 64 + lane) * 8];
                v8s bl = *(const v8s*)&Wlo[(kk * 64 + lane) * 8];
                acc1 = __builtin_amdgcn_mfma_f32_16x16x32_bf16(a[kk], bh, acc1, 0, 0, 0);
                acc2 = __builtin_amdgcn_mfma_f32_16x16x32_bf16(a[kk], bl, acc2, 0, 0, 0);
            }
#pragma unroll
            for (int rg = 0; rg < 4; ++rg) {
                int node = tile * 16 + quad * 4 + rg;
                if (node < n_nodes)
                    m1[(size_t)node * HID + col] = f2bf(acc1[rg] + acc2[rg]);
            }
        }
    } else {
        const float* x = (const float*)xp_;
        for (int tile = vb * 8 + wave; tile < n_tiles; tile += g_gemm * 8) {
            int row = tile * 16 + col;
            int r = row < n_nodes ? row : n_nodes - 1;
            const float* xp = x + (size_t)r * IN_DIM + quad * 8;
            float4 u[16];
#pragma unroll
            for (int kk = 0; kk < 8; ++kk) {
                u[2 * kk]     = *(const float4*)(xp + kk * 32);
                u[2 * kk + 1] = *(const float4*)(xp + kk * 32 + 4);
            }
            v4f acc1 = {0.f, 0.f, 0.f, 0.f};   // ahi*bh chain
            v4f acc2 = {0.f, 0.f, 0.f, 0.f};   // ahi*bl + alo*bh chain
#pragma unroll
            for (int kk = 0; kk < 8; ++kk) {
                union { unsigned int w[4]; v8s v; } ahi, alo;
#pragma unroll
                for (int pj = 0; pj < 2; ++pj) {
                    float4 ff = u[2 * kk + pj];
                    split2(ff.x, ff.y, ahi.w[2 * pj],     alo.w[2 * pj]);
                    split2(ff.z, ff.w, ahi.w[2 * pj + 1], alo.w[2 * pj + 1]);
                }
                v8s bh = *(const v8s*)&Whi[(kk * 64 + lane) * 8];
                v8s bl = *(const v8s*)&Wlo[(kk * 64 + lane) * 8];
                acc1 = __builtin_amdgcn_mfma_f32_16x16x32_bf16(ahi.v, bh, acc1, 0, 0, 0);
                acc2 = __builtin_amdgcn_mfma_f32_16x16x32_bf16(ahi.v, bl, acc2, 0, 0, 0);
                acc2 = __builtin_amdgcn_mfma_f32_16x16x32_bf16(alo.v, bh, acc2, 0, 0, 0);
            }
#pragma unroll
            for (int rg = 0; rg < 4; ++rg) {
                int node = tile * 16 + quad * 4 + rg;
                if (node < n_nodes)
                    m1[(size_t)node * HID + col] = f2bf(acc1[rg] + acc2[rg]);
            }
        }
    }
}

// ---------------- K3: csr build + agg1 fused (1024 thr, one block/bucket) ---
// 1024 threads halve every per-block serial phase vs 512 (8 atomics/thread,
// agg covers all 256 nodes in one round). LDS 37KB -> 2 blocks/CU (thread
// cap), 391 blocks all resident.
__global__ __launch_bounds__(1024) void csr_agg1_kernel(
        const unsigned int* __restrict__ pairs,
        const int* __restrict__ bucket_off,
        const unsigned short* __restrict__ m1,
        const void* __restrict__ b1p,
        int* __restrict__ row_off, int* __restrict__ csr_src,
        unsigned short* __restrict__ h,
        int n_nodes, const int* __restrict__ flags) {
    __shared__ unsigned int ssrc[SSRC_CAP];   // 34 KiB sorted src list
    __shared__ int deg[BKT_W];
    __shared__ int cur[BKT_W];
    __shared__ int ts[BKT_W];
    int blk = blockIdx.x;
    int nbase = blk << BKT_SHIFT;
    int NL = n_nodes - nbase; if (NL > BKT_W) NL = BKT_W;
    int beg = bucket_off[blk], end = bucket_off[blk + 1];
    int t = threadIdx.x;

    if (t < BKT_W) deg[t] = 0;
    __syncthreads();
    for (int k = beg + t; k < end; k += 1024)
        atomicAdd(&deg[pairs[k] & (BKT_W - 1)], 1);
    __syncthreads();
    if (t < BKT_W) ts[t] = deg[t];
    __syncthreads();
    for (int off = 1; off < BKT_W; off <<= 1) {
        int v = 0;
        if (t < BKT_W && t >= off) v = ts[t - off];
        __syncthreads();
        if (t < BKT_W) ts[t] += v;
        __syncthreads();
    }
    if (t < BKT_W) {
        int exl = ts[t] - deg[t];
        cur[t] = exl;
        if (t < NL) row_off[nbase + t] = beg + exl;
    }
    __syncthreads();
    // placement: global csr_src (for agg2) + LDS copy (for the fused agg1)
    for (int k = beg + t; k < end; k += 1024) {
        unsigned int pr = pairs[k];
        int dl = pr & (BKT_W - 1);
        int pos = atomicAdd(&cur[dl], 1);
        int src = (int)(pr >> 8);
        csr_src[beg + pos] = src;
        if (pos < SSRC_CAP) ssrc[pos] = (unsigned)src;
    }
    __syncthreads();

    // ---- fused agg1: 4 lanes per node, 256 node-groups (1 round) ----
    const int wf32 = flags[2];
    int q = t & 3, grp = t >> 2;
    float b0, b1v, b2v, b3;
    if (wf32) {
        const float* b = (const float*)b1p + q * 4;
        b0 = b[0]; b1v = b[1]; b2v = b[2]; b3 = b[3];
    } else {
        const unsigned short* b = (const unsigned short*)b1p + q * 4;
        b0 = bf2f(b[0]); b1v = bf2f(b[1]); b2v = bf2f(b[2]); b3 = bf2f(b[3]);
    }
    for (int nl = grp; nl < NL; nl += 256) {
        int sL = ts[nl] - deg[nl];
        int eL = ts[nl];
        float a0 = 0.f, a1 = 0.f, a2 = 0.f, a3 = 0.f;
        int k = sL;
        for (; k + 8 <= eL; k += 8) {
            int sidx[8];
            uint2 v[8];
#pragma unroll
            for (int u = 0; u < 8; ++u)
                sidx[u] = (k + u < SSRC_CAP) ? (int)ssrc[k + u]
                                             : csr_src[beg + k + u];
#pragma unroll
            for (int u = 0; u < 8; ++u)
                v[u] = *(const uint2*)(m1 + (size_t)sidx[u] * HID + q * 4);
#pragma unroll
            for (int u = 0; u < 8; ++u) {
                a0 += bf2f((unsigned short)(v[u].x));
                a1 += bf2f((unsigned short)(v[u].x >> 16));
                a2 += bf2f((unsigned short)(v[u].y));
                a3 += bf2f((unsigned short)(v[u].y >> 16));
            }
        }
        for (; k < eL; ++k) {
            int s = (k < SSRC_CAP) ? (int)ssrc[k] : csr_src[beg + k];
            uint2 v = *(const uint2*)(m1 + (size_t)s * HID + q * 4);
            a0 += bf2f((unsigned short)(v.x));
            a1 += bf2f((unsigned short)(v.x >> 16));
            a2 += bf2f((unsigned short)(v.y));
            a3 += bf2f((unsigned short)(v.y >> 16));
        }
        float r0 = fmaxf(a0 + b0, 0.f);
        float r1 = fmaxf(a1 + b1v, 0.f);
        float r2 = fmaxf(a2 + b2v, 0.f);
        float r3 = fmaxf(a3 + b3, 0.f);
        uint2 packed;
        packed.x = (unsigned int)f2bf(r0) | ((unsigned int)f2bf(r1) << 16);
        packed.y = (unsigned int)f2bf(r2) | ((unsigned int)f2bf(r3) << 16);
        *(uint2*)(h + (size_t)(nbase + nl) * HID + q * 4) = packed;
    }
}

// ---------------- gather-sum core: 4 lanes/node, bf16 rows, 16-deep MLP -----
__device__ __forceinline__ v4f gather_bf16(const unsigned short* __restrict__ src,
                                           const int* __restrict__ csr_src,
                                           int beg, int end, int q) {
    float a0 = 0.f, a1 = 0.f, a2 = 0.f, a3 = 0.f;
    int k = beg;
    for (; k + 16 <= end; k += 16) {
        uint2 v[16];
#pragma unroll
        for (int u = 0; u < 16; ++u) {
            int s = csr_src[k + u];
            v[u] = *(const uint2*)(src + (size_t)s * HID + q * 4);
        }
#pragma unroll
        for (int u = 0; u < 16; ++u) {
            a0 += bf2f((unsigned short)(v[u].x));
            a1 += bf2f((unsigned short)(v[u].x >> 16));
            a2 += bf2f((unsigned short)(v[u].y));
            a3 += bf2f((unsigned short)(v[u].y >> 16));
        }
    }
    for (; k + 4 <= end; k += 4) {
        uint2 v[4];
#pragma unroll
        for (int u = 0; u < 4; ++u) {
            int s = csr_src[k + u];
            v[u] = *(const uint2*)(src + (size_t)s * HID + q * 4);
        }
#pragma unroll
        for (int u = 0; u < 4; ++u) {
            a0 += bf2f((unsigned short)(v[u].x));
            a1 += bf2f((unsigned short)(v[u].x >> 16));
            a2 += bf2f((unsigned short)(v[u].y));
            a3 += bf2f((unsigned short)(v[u].y >> 16));
        }
    }
    for (; k < end; ++k) {
        int s = csr_src[k];
        uint2 v = *(const uint2*)(src + (size_t)s * HID + q * 4);
        a0 += bf2f((unsigned short)(v.x));
        a1 += bf2f((unsigned short)(v.x >> 16));
        a2 += bf2f((unsigned short)(v.y));
        a3 += bf2f((unsigned short)(v.y >> 16));
    }
    v4f r = {a0, a1, a2, a3};
    return r;
}

// ---------------- agg2 + out fused: out = (A . h) @ W2 + b2 -----------------
__global__ void agg2_out_kernel(const unsigned short* __restrict__ h,
                                const int* __restrict__ row_off,
                                const int* __restrict__ csr_src,
                                const void* __restrict__ W2p,
                                const void* __restrict__ b2p,
                                void* __restrict__ out, int n_nodes,
                                const int* __restrict__ flags) {
    __shared__ float Ws[HID * OUTD];
    __shared__ float bs[OUTD];
    const int xf32 = flags[1], wf32 = flags[2];
    if (threadIdx.x < HID * OUTD)
        Ws[threadIdx.x] = wf32 ? ((const float*)W2p)[threadIdx.x]
                               : bf2f(((const unsigned short*)W2p)[threadIdx.x]);
    if (threadIdx.x < OUTD)
        bs[threadIdx.x] = wf32 ? ((const float*)b2p)[threadIdx.x]
                               : bf2f(((const unsigned short*)b2p)[threadIdx.x]);
    __syncthreads();

    int t = blockIdx.x * blockDim.x + threadIdx.x;
    int node = t >> 2;
    if (node >= n_nodes) return;
    int q = t & 3;
    v4f a = gather_bf16(h, csr_src, row_off[node], row_off[node + 1], q);

    float o[OUTD];
#pragma unroll
    for (int od = 0; od < OUTD; ++od) {
        float s = 0.f;
#pragma unroll
        for (int j = 0; j < 4; ++j)
            s = fmaf(a[j], Ws[(q * 4 + j) * OUTD + od], s);
        o[od] = s;
    }
#pragma unroll
    for (int od = 0; od < OUTD; ++od) {
        o[od] += __shfl_xor(o[od], 1);
        o[od] += __shfl_xor(o[od], 2);
        o[od] += bs[od];
    }

    if (xf32) {
        float2* po = (float2*)((float*)out + (size_t)node * OUTD);
        if (q == 0) {
            po[0] = make_float2(o[0], o[1]);
            po[1] = make_float2(o[2], o[3]);
        } else if (q == 1) {
            po[2] = make_float2(o[4], o[5]);
            po[3] = make_float2(o[6], o[7]);
        } else if (q == 2) {
            po[4] = make_float2(o[8], o[9]);
        }
    } else {
        unsigned int* po = (unsigned int*)((unsigned short*)out + (size_t)node * OUTD);
        if (q == 0) {
            po[0] = (unsigned int)f2bf(o[0]) | ((unsigned int)f2bf(o[1]) << 16);
            po[1] = (unsigned int)f2bf(o[2]) | ((unsigned int)f2bf(o[3]) << 16);
        } else if (q == 1) {
            po[2] = (unsigned int)f2bf(o[4]) | ((unsigned int)f2bf(o[5]) << 16);
            po[3] = (unsigned int)f2bf(o[6]) | ((unsigned int)f2bf(o[7]) << 16);
        } else if (q == 2) {
            po[4] = (unsigned int)f2bf(o[8]) | ((unsigned int)f2bf(o[9]) << 16);
        }
    }
}

// ---------------- Sentinel: ws_size too small -------------------------------
__global__ void sentinel_kernel(float* __restrict__ out) {
    if (blockIdx.x == 0 && threadIdx.x < 16) out[threadIdx.x] = 123456.0f;
}

extern "C" void kernel_launch(void* const* d_in, const int* in_sizes, int n_in,
                              void* d_out, int out_size, void* d_ws, size_t ws_size,
                              hipStream_t stream) {
    const void* x  = d_in[0];
    const void* ei = d_in[1];
    const void* W1 = d_in[2];
    const void* b1 = d_in[3];
    const void* W2 = d_in[4];
    const void* b2 = d_in[5];

    const int n_nodes = in_sizes[0] / IN_DIM;        // 100000
    const int n_edges = in_sizes[1] / 2;             // 3200000
    const int K = (n_nodes + BKT_W - 1) / BKT_W;     // 391 buckets

    // Workspace layout (256B-aligned). gemm1 overlaps part -> m1/h do not
    // alias pairs.
    char* p = (char*)d_ws;
    auto align = [](size_t v) { return (v + 255) & ~(size_t)255; };
    size_t off = 0;
    int* flags      = (int*)(p + off); off = align(off + 256);
    unsigned short* w1split = (unsigned short*)(p + off); off = align(off + 8192 * 2);
    int* bucket_cnt = (int*)(p + off); off = align(off + (size_t)K * 4);
    int* bucket_off = (int*)(p + off); off = align(off + ((size_t)K + 1) * 4);
    int* bcur       = (int*)(p + off); off = align(off + (size_t)K * 4);
    int* row_off    = (int*)(p + off); off = align(off + ((size_t)n_nodes + 1) * 4);
    int* csr_src    = (int*)(p + off); off = align(off + (size_t)n_edges * 4);
    unsigned int* pairs = (unsigned int*)(p + off); off = align(off + (size_t)n_edges * 4);
    unsigned short* m1 = (unsigned short*)(p + off); off = align(off + (size_t)n_nodes * HID * 2);
    unsigned short* h  = (unsigned short*)(p + off); off = align(off + (size_t)n_nodes * HID * 2);

    if (ws_size < off) {
        sentinel_kernel<<<1, 64, 0, stream>>>((float*)d_out);
        return;
    }

    const int n_tiles16 = (n_nodes + 15) >> 4;        // 6250
    const int g_gemm = (n_tiles16 + 7) / 8;           // 782 (1 tile/wave, 8 waves)
    const int g_part = (n_edges + PART_CH - 1) / PART_CH;  // 391

    // 0. zero bucket counters
    zero_kernel<<<1, 256, 0, stream>>>(bucket_cnt, K);

    // 1. K1 fat: flags + W1 split + bucket histogram
    setup_bhist_kernel<<<17 + G_HIST, 256, 0, stream>>>(
        x, W1, ei, n_nodes, n_edges, flags, bucket_cnt, K, w1split);

    // 2. bucket scan
    bscan_kernel<<<1, 256, 0, stream>>>(bucket_cnt, K, bucket_off, bcur,
                                        row_off, n_nodes, n_edges);

    // 3. K2 fat: partition overlapped with gemm1 (512-thread blocks)
    part_gemm1_kernel<<<g_part + g_gemm, 512, 0, stream>>>(
        ei, n_edges, bcur, pairs, x, w1split, m1, n_nodes, flags, K, g_part);

    // 4. K3: per-bucket CSR build + layer-1 aggregation fused (1024 thr)
    csr_agg1_kernel<<<K, 1024, 0, stream>>>(pairs, bucket_off, m1, b1,
                                            row_off, csr_src, h, n_nodes, flags);

    // 5. layer 2 aggregation + output GEMM fused
    {
        long long threads = (long long)n_nodes * 4;
        agg2_out_kernel<<<(int)((threads + 255) / 256), 256, 0, stream>>>(
            h, row_off, csr_src, W2, b2, d_out, n_nodes, flags);
    }
}

// Round 12
// 288.964 us; speedup vs baseline: 1.5014x; 1.0034x over previous
//
#include <hip/hip_runtime.h>
#include <hip/hip_bf16.h>
#include <stdint.h>

#define IN_DIM 256
#define HID 16
#define OUTD 10
#define BKT_SHIFT 8            // 256 nodes per bucket
#define BKT_W 256
#define PART_CH 8192           // edges per partition block (fixed-cost amortize)
#define EPT 16                 // edges per thread in part (PART_CH/512)
#define G_HIST 512             // histogram blocks in K1
#define G_PREF 512             // x L3-prefetch blocks in K1
#define SSRC_CAP 8704          // csr_agg1 LDS src capacity (mean 8192 + ~5 sigma)

typedef short v8s __attribute__((ext_vector_type(8)));
typedef float v4f __attribute__((ext_vector_type(4)));

__device__ __forceinline__ float bf2f(unsigned short u) {
    return __uint_as_float(((unsigned int)u) << 16);
}
__device__ __forceinline__ unsigned short f2bf(float f) {
    unsigned int u = __float_as_uint(f);
    unsigned int lsb = (u >> 16) & 1u;
    u += 0x7fffu + lsb;  // round-to-nearest-even
    return (unsigned short)(u >> 16);
}

// split a float pair into packed-bf16 (hi,lo) via v_perm_b32: 6 ops / 2 elems.
__device__ __forceinline__ void split2(float f0, float f1,
                                       unsigned int& hi2, unsigned int& lo2) {
    unsigned int u0 = __float_as_uint(f0);
    unsigned int u1 = __float_as_uint(f1);
    hi2 = __builtin_amdgcn_perm(u1, u0, 0x07060302u);   // [u0.hi16, u1.hi16]
    float h0 = __uint_as_float(u0 & 0xFFFF0000u);
    float h1 = __uint_as_float(u1 & 0xFFFF0000u);
    unsigned int l0 = __float_as_uint(f0 - h0);
    unsigned int l1 = __float_as_uint(f1 - h1);
    lo2 = __builtin_amdgcn_perm(l1, l0, 0x07060302u);
}

__device__ __forceinline__ int load_dst(const void* ei, int n_edges, int e, int is64) {
    return is64 ? (int)((const long long*)ei)[(size_t)n_edges + e]
                : ((const int*)ei)[(size_t)n_edges + e];
}
__device__ __forceinline__ int load_src(const void* ei, int n_edges, int e, int is64) {
    return is64 ? (int)((const long long*)ei)[e] : ((const int*)ei)[e];
}

// ---------------- zero: bucket counters (plain kernel, no memset API) -------
__global__ void zero_kernel(int* __restrict__ bucket_cnt, int K) {
    for (int i = threadIdx.x; i < K; i += blockDim.x) bucket_cnt[i] = 0;
}

// ---------------- K1 fat: setup/flags/W1-split + bhist + x-prefetch ---------
// Blocks 0..15: W1 split. Block 16: flags. Blocks 17..17+G_HIST-1: bucket
// histogram. Blocks 17+G_HIST..: stream-touch x -> pulls all of x into the
// 256MB L3 so K2's latency-bound gemm x-reads become L3 hits (~300cy vs
// ~900cy HBM miss). x 102MB + ei 51MB < 256MB -> stays resident through K2.
__global__ void setup_bhist_kernel(const void* __restrict__ x,
                                   const void* __restrict__ W1,
                                   const void* __restrict__ ei,
                                   int n_nodes, int n_edges, int x_bytes,
                                   int* __restrict__ flags,
                                   int* __restrict__ bucket_cnt, int K,
                                   unsigned short* __restrict__ W1split) {
    __shared__ int lh[512];
    __shared__ int sflag;
    int b = blockIdx.x, t = threadIdx.x;

    if (b < 16) {
        // ---- W1 split role (local wf32 detect over first 256 values) ----
        if (t == 0) sflag = 0;
        __syncthreads();
        {
            float vw = bf2f(((const unsigned short*)W1)[t]);
            if (!(vw > -1e4f && vw < 1e4f)) sflag = 1;   // benign same-value race
        }
        __syncthreads();
        const int wf32 = sflag;
        int i = b * 256 + t;                       // 0..4095 (i = k*16 + n)
        float w = wf32 ? ((const float*)W1)[i]
                       : bf2f(((const unsigned short*)W1)[i]);
        unsigned short hi = f2bf(w);
        unsigned short lo = f2bf(w - bf2f(hi));
        int k = i >> 4, n = i & 15;
        int kk = k >> 5, qd = (k >> 3) & 3, j = k & 7;
        int idx = ((kk * 4 + qd) * 16 + n) * 8 + j;  // = (kk*64 + lane)*8 + j
        W1split[idx] = hi;
        W1split[4096 + idx] = lo;
        return;
    }
    if (b == 16) {
        // ---- global flags role ----
        if (t < 64) {
            const unsigned short* xs = (const unsigned short*)x;
            const unsigned short* ws = (const unsigned short*)W1;
            bool badx = false, badw = false;
#pragma unroll
            for (int q = 0; q < 4; ++q) {
                float vx = bf2f(xs[t + 64 * q]);
                float vw = bf2f(ws[t + 64 * q]);
                if (!(vx > -1e4f && vx < 1e4f)) badx = true;
                if (!(vw > -1e4f && vw < 1e4f)) badw = true;
            }
            const unsigned long long* e64 = (const unsigned long long*)ei;
            bool big = false;
#pragma unroll
            for (int q = 0; q < 2; ++q)
                if (e64[t + 64 * q] >= (unsigned long long)n_nodes) big = true;
            int xf32 = __any(badx) ? 1 : 0;
            int wf32 = __any(badw) ? 1 : 0;
            int is64 = __any(big) ? 0 : 1;
            if (t == 0) { flags[0] = is64; flags[1] = xf32; flags[2] = wf32; }
        }
        return;
    }
    if (b >= 17 + G_HIST) {
        // ---- x prefetch role: dtype-agnostic byte-range stream touch ----
        const float4* x4 = (const float4*)x;
        int n4 = x_bytes >> 4;
        int vb = b - 17 - G_HIST;
        float acc = 0.f;
        for (int i = vb * 256 + t; i < n4; i += G_PREF * 256) {
            float4 v = x4[i];
            acc += v.x + v.y + v.z + v.w;
        }
        // keep loads observable; condition is never true in practice
        if (__float_as_uint(acc) == 0xDEADBEEFu) flags[32] = 1;
        return;
    }

    // ---- bhist role (local is64 detect over first 128 u64 reads) ----
    if (t == 0) sflag = 1;
    __syncthreads();
    {
        const unsigned long long* e64 = (const unsigned long long*)ei;
        if (t < 128 && e64[t] >= (unsigned long long)n_nodes) sflag = 0;
    }
    __syncthreads();
    const int is64 = sflag;
    for (int i = t; i < 512; i += 256) lh[i] = 0;
    __syncthreads();
    int vbid = b - 17;
    int stride = G_HIST * 256;
    for (int e = vbid * 256 + t; e < n_edges; e += stride) {
        int d = load_dst(ei, n_edges, e, is64);
        atomicAdd(&lh[d >> BKT_SHIFT], 1);
    }
    __syncthreads();
    for (int i = t; i < K; i += 256)
        if (lh[i]) atomicAdd(&bucket_cnt[i], lh[i]);
}

// ---------------- bucket scan (1 block) -------------------------------------
__global__ void bscan_kernel(const int* __restrict__ bucket_cnt, int K,
                             int* __restrict__ bucket_off, int* __restrict__ bcur,
                             int* __restrict__ row_off, int n_nodes, int n_edges) {
    __shared__ int ts[256];
    int t = threadIdx.x;
    const int KP = (K + 255) / 256;   // <= 8
    int base = t * KP;
    int local[8];
    int s = 0;
    for (int q = 0; q < KP; ++q) {
        int idx = base + q;
        int v = (idx < K) ? bucket_cnt[idx] : 0;
        local[q] = v; s += v;
    }
    ts[t] = s;
    __syncthreads();
    for (int off = 1; off < 256; off <<= 1) {
        int v = (t >= off) ? ts[t - off] : 0;
        __syncthreads();
        ts[t] += v;
        __syncthreads();
    }
    int ex = ts[t] - s;
    for (int q = 0; q < KP; ++q) {
        int idx = base + q;
        if (idx < K) { bucket_off[idx] = ex; bcur[idx] = ex; }
        ex += local[q];
    }
    if (t == 255) bucket_off[K] = ex;
    if (t == 0) row_off[n_nodes] = n_edges;
}

// ---------------- K2 fat: part (blocks < g_part, 512thr) + gemm1 ------------
// part: in-LDS counting sort, PART_CH=8192. sbkt dropped: flush derives the
// bucket via 9-step binary search over lh (post-placement lh = inclusive run
// ends). LDS 53->37KB => 4 blocks/CU (was 3), +33% resident waves for the
// latency-bound gemm role.
__global__ __launch_bounds__(512, 4) void part_gemm1_kernel(
        const void* __restrict__ ei, int n_edges,
        int* __restrict__ bcur, unsigned int* __restrict__ pairs,
        const void* __restrict__ xp_,
        const unsigned short* __restrict__ W1split,
        unsigned short* __restrict__ m1, int n_nodes,
        const int* __restrict__ flags, int K, int g_part) {
    __shared__ int lh[512];                  // counts -> scan -> cursor -> run-ends
    __shared__ int gdelta[512];              // gstart[b] - lstart[b]
    __shared__ unsigned int spairs[PART_CH]; // 32 KiB
    int t = threadIdx.x;

    if ((int)blockIdx.x < g_part) {
        // ---------- partition role (512 threads, 1 bucket-entry each) ----------
        int begin = blockIdx.x * PART_CH;
        int is64 = flags[0];
        lh[t] = 0;

        int dloc[EPT];
#pragma unroll
        for (int i = 0; i < EPT; ++i) {
            int e = begin + i * 512 + t;
            dloc[i] = (e < n_edges) ? load_dst(ei, n_edges, e, is64) : -1;
        }
        __syncthreads();
#pragma unroll
        for (int i = 0; i < EPT; ++i)
            if (dloc[i] >= 0) atomicAdd(&lh[dloc[i] >> BKT_SHIFT], 1);
        __syncthreads();

        // in-place Hillis-Steele inclusive scan of lh[512] (c kept in register)
        int c = lh[t];
        for (int off = 1; off < 512; off <<= 1) {
            int add = (t >= off) ? lh[t - off] : 0;
            __syncthreads();
            lh[t] += add;
            __syncthreads();
        }
        int ex = lh[t] - c;
        if (c > 0) gdelta[t] = atomicAdd(&bcur[t], c) - ex;
        lh[t] = ex;             // own-slot overwrite -> becomes placement cursor
        __syncthreads();        // publishes gdelta + cursors

        // place into LDS, sorted by bucket (lh[b] ends at inclusive run end)
#pragma unroll
        for (int i = 0; i < EPT; ++i) {
            int e = begin + i * 512 + t;
            if (dloc[i] >= 0) {
                int srcv = load_src(ei, n_edges, e, is64);
                int bb = dloc[i] >> BKT_SHIFT;
                int lpos = atomicAdd(&lh[bb], 1);
                spairs[lpos] = ((unsigned)srcv << 8) | ((unsigned)dloc[i] & (BKT_W - 1));
            }
        }
        __syncthreads();

        // coalesced flush; bucket of slot j = first b with lh[b] > j
        int total = n_edges - begin; if (total > PART_CH) total = PART_CH;
        for (int j = t; j < total; j += 512) {
            unsigned int pv = spairs[j];
            int bb = 0;
#pragma unroll
            for (int s = 256; s > 0; s >>= 1)
                if (lh[bb + s - 1] <= j) bb += s;
            pairs[gdelta[bb] + j] = pv;
        }
        return;
    }

    // ---------- gemm1 role (8 waves/block) ----------
    const int xf32 = flags[1];
    int vb = blockIdx.x - g_part;
    int g_gemm = gridDim.x - g_part;
    int lane = t & 63;
    int wave = t >> 6;                 // 0..7
    int col  = lane & 15;
    int quad = lane >> 4;
    int n_tiles = (n_nodes + 15) >> 4;
    const unsigned short* Whi = W1split;
    const unsigned short* Wlo = W1split + 4096;

    if (!xf32) {
        const unsigned short* x = (const unsigned short*)xp_;
        for (int tile = vb * 8 + wave; tile < n_tiles; tile += g_gemm * 8) {
            int row = tile * 16 + col;
            int r = row < n_nodes ? row : n_nodes - 1;
            const unsigned short* xp = x + (size_t)r * IN_DIM + quad * 8;
            v8s a[8];
#pragma unroll
            for (int kk = 0; kk < 8; ++kk)
                a[kk] = *(const v8s*)(xp + kk * 32);
            v4f acc1 = {0.f, 0.f, 0.f, 0.f};
            v4f acc2 = {0.f, 0.f, 0.f, 0.f};
#pragma unroll
            for (int kk = 0; kk < 8; ++kk) {
                v8s bh = *(const v8s*)&Whi[(kk * 64 + lane) * 8];
                v8s bl = *(const v8s*)&Wlo[(kk * 64 + lane) * 8];
                acc1 = __builtin_amdgcn_mfma_f32_16x16x32_bf16(a[kk], bh, acc1, 0, 0, 0);
                acc2 = __builtin_amdgcn_mfma_f32_16x16x32_bf16(a[kk], bl, acc2, 0, 0, 0);
            }
#pragma unroll
            for (int rg = 0; rg < 4; ++rg) {
                int node = tile * 16 + quad * 4 + rg;
                if (node < n_nodes)
                    m1[(size_t)node * HID + col] = f2bf(acc1[rg] + acc2[rg]);
            }
        }
    } else {
        const float* x = (const float*)xp_;
        for (int tile = vb * 8 + wave; tile < n_tiles; tile += g_gemm * 8) {
            int row = tile * 16 + col;
            int r = row < n_nodes ? row : n_nodes - 1;
            const float* xp = x + (size_t)r * IN_DIM + quad * 8;
            float4 u[16];
#pragma unroll
            for (int kk = 0; kk < 8; ++kk) {
                u[2 * kk]     = *(const float4*)(xp + kk * 32);
                u[2 * kk + 1] = *(const float4*)(xp + kk * 32 + 4);
            }
            v4f acc1 = {0.f, 0.f, 0.f, 0.f};   // ahi*bh chain
            v4f acc2 = {0.f, 0.f, 0.f, 0.f};   // ahi*bl + alo*bh chain
#pragma unroll
            for (int kk = 0; kk < 8; ++kk) {
                union { unsigned int w[4]; v8s v; } ahi, alo;
#pragma unroll
                for (int pj = 0; pj < 2; ++pj) {
                    float4 ff = u[2 * kk + pj];
                    split2(ff.x, ff.y, ahi.w[2 * pj],     alo.w[2 * pj]);
                    split2(ff.z, ff.w, ahi.w[2 * pj + 1], alo.w[2 * pj + 1]);
                }
                v8s bh = *(const v8s*)&Whi[(kk * 64 + lane) * 8];
                v8s bl = *(const v8s*)&Wlo[(kk * 64 + lane) * 8];
                acc1 = __builtin_amdgcn_mfma_f32_16x16x32_bf16(ahi.v, bh, acc1, 0, 0, 0);
                acc2 = __builtin_amdgcn_mfma_f32_16x16x32_bf16(ahi.v, bl, acc2, 0, 0, 0);
                acc2 = __builtin_amdgcn_mfma_f32_16x16x32_bf16(alo.v, bh, acc2, 0, 0, 0);
            }
#pragma unroll
            for (int rg = 0; rg < 4; ++rg) {
                int node = tile * 16 + quad * 4 + rg;
                if (node < n_nodes)
                    m1[(size_t)node * HID + col] = f2bf(acc1[rg] + acc2[rg]);
            }
        }
    }
}

// ---------------- K3: csr build + agg1 fused (1024 thr, one block/bucket) ---
__global__ __launch_bounds__(1024) void csr_agg1_kernel(
        const unsigned int* __restrict__ pairs,
        const int* __restrict__ bucket_off,
        const unsigned short* __restrict__ m1,
        const void* __restrict__ b1p,
        int* __restrict__ row_off, int* __restrict__ csr_src,
        unsigned short* __restrict__ h,
        int n_nodes, const int* __restrict__ flags) {
    __shared__ unsigned int ssrc[SSRC_CAP];   // 34 KiB sorted src list
    __shared__ int deg[BKT_W];
    __shared__ int cur[BKT_W];
    __shared__ int ts[BKT_W];
    int blk = blockIdx.x;
    int nbase = blk << BKT_SHIFT;
    int NL = n_nodes - nbase; if (NL > BKT_W) NL = BKT_W;
    int beg = bucket_off[blk], end = bucket_off[blk + 1];
    int t = threadIdx.x;

    if (t < BKT_W) deg[t] = 0;
    __syncthreads();
    for (int k = beg + t; k < end; k += 1024)
        atomicAdd(&deg[pairs[k] & (BKT_W - 1)], 1);
    __syncthreads();
    if (t < BKT_W) ts[t] = deg[t];
    __syncthreads();
    for (int off = 1; off < BKT_W; off <<= 1) {
        int v = 0;
        if (t < BKT_W && t >= off) v = ts[t - off];
        __syncthreads();
        if (t < BKT_W) ts[t] += v;
        __syncthreads();
    }
    if (t < BKT_W) {
        int exl = ts[t] - deg[t];
        cur[t] = exl;
        if (t < NL) row_off[nbase + t] = beg + exl;
    }
    __syncthreads();
    // placement: global csr_src (for agg2) + LDS copy (for the fused agg1)
    for (int k = beg + t; k < end; k += 1024) {
        unsigned int pr = pairs[k];
        int dl = pr & (BKT_W - 1);
        int pos = atomicAdd(&cur[dl], 1);
        int src = (int)(pr >> 8);
        csr_src[beg + pos] = src;
        if (pos < SSRC_CAP) ssrc[pos] = (unsigned)src;
    }
    __syncthreads();

    // ---- fused agg1: 4 lanes per node, 256 node-groups (1 round) ----
    const int wf32 = flags[2];
    int q = t & 3, grp = t >> 2;
    float b0, b1v, b2v, b3;
    if (wf32) {
        const float* b = (const float*)b1p + q * 4;
        b0 = b[0]; b1v = b[1]; b2v = b[2]; b3 = b[3];
    } else {
        const unsigned short* b = (const unsigned short*)b1p + q * 4;
        b0 = bf2f(b[0]); b1v = bf2f(b[1]); b2v = bf2f(b[2]); b3 = bf2f(b[3]);
    }
    for (int nl = grp; nl < NL; nl += 256) {
        int sL = ts[nl] - deg[nl];
        int eL = ts[nl];
        float a0 = 0.f, a1 = 0.f, a2 = 0.f, a3 = 0.f;
        int k = sL;
        for (; k + 8 <= eL; k += 8) {
            int sidx[8];
            uint2 v[8];
#pragma unroll
            for (int u = 0; u < 8; ++u)
                sidx[u] = (k + u < SSRC_CAP) ? (int)ssrc[k + u]
                                             : csr_src[beg + k + u];
#pragma unroll
            for (int u = 0; u < 8; ++u)
                v[u] = *(const uint2*)(m1 + (size_t)sidx[u] * HID + q * 4);
#pragma unroll
            for (int u = 0; u < 8; ++u) {
                a0 += bf2f((unsigned short)(v[u].x));
                a1 += bf2f((unsigned short)(v[u].x >> 16));
                a2 += bf2f((unsigned short)(v[u].y));
                a3 += bf2f((unsigned short)(v[u].y >> 16));
            }
        }
        for (; k < eL; ++k) {
            int s = (k < SSRC_CAP) ? (int)ssrc[k] : csr_src[beg + k];
            uint2 v = *(const uint2*)(m1 + (size_t)s * HID + q * 4);
            a0 += bf2f((unsigned short)(v.x));
            a1 += bf2f((unsigned short)(v.x >> 16));
            a2 += bf2f((unsigned short)(v.y));
            a3 += bf2f((unsigned short)(v.y >> 16));
        }
        float r0 = fmaxf(a0 + b0, 0.f);
        float r1 = fmaxf(a1 + b1v, 0.f);
        float r2 = fmaxf(a2 + b2v, 0.f);
        float r3 = fmaxf(a3 + b3, 0.f);
        uint2 packed;
        packed.x = (unsigned int)f2bf(r0) | ((unsigned int)f2bf(r1) << 16);
        packed.y = (unsigned int)f2bf(r2) | ((unsigned int)f2bf(r3) << 16);
        *(uint2*)(h + (size_t)(nbase + nl) * HID + q * 4) = packed;
    }
}

// ---------------- gather-sum core: 4 lanes/node, bf16 rows, 16-deep MLP -----
__device__ __forceinline__ v4f gather_bf16(const unsigned short* __restrict__ src,
                                           const int* __restrict__ csr_src,
                                           int beg, int end, int q) {
    float a0 = 0.f, a1 = 0.f, a2 = 0.f, a3 = 0.f;
    int k = beg;
    for (; k + 16 <= end; k += 16) {
        uint2 v[16];
#pragma unroll
        for (int u = 0; u < 16; ++u) {
            int s = csr_src[k + u];
            v[u] = *(const uint2*)(src + (size_t)s * HID + q * 4);
        }
#pragma unroll
        for (int u = 0; u < 16; ++u) {
            a0 += bf2f((unsigned short)(v[u].x));
            a1 += bf2f((unsigned short)(v[u].x >> 16));
            a2 += bf2f((unsigned short)(v[u].y));
            a3 += bf2f((unsigned short)(v[u].y >> 16));
        }
    }
    for (; k + 4 <= end; k += 4) {
        uint2 v[4];
#pragma unroll
        for (int u = 0; u < 4; ++u) {
            int s = csr_src[k + u];
            v[u] = *(const uint2*)(src + (size_t)s * HID + q * 4);
        }
#pragma unroll
        for (int u = 0; u < 4; ++u) {
            a0 += bf2f((unsigned short)(v[u].x));
            a1 += bf2f((unsigned short)(v[u].x >> 16));
            a2 += bf2f((unsigned short)(v[u].y));
            a3 += bf2f((unsigned short)(v[u].y >> 16));
        }
    }
    for (; k < end; ++k) {
        int s = csr_src[k];
        uint2 v = *(const uint2*)(src + (size_t)s * HID + q * 4);
        a0 += bf2f((unsigned short)(v.x));
        a1 += bf2f((unsigned short)(v.x >> 16));
        a2 += bf2f((unsigned short)(v.y));
        a3 += bf2f((unsigned short)(v.y >> 16));
    }
    v4f r = {a0, a1, a2, a3};
    return r;
}

// ---------------- agg2 + out fused: out = (A . h) @ W2 + b2 -----------------
__global__ void agg2_out_kernel(const unsigned short* __restrict__ h,
                                const int* __restrict__ row_off,
                                const int* __restrict__ csr_src,
                                const void* __restrict__ W2p,
                                const void* __restrict__ b2p,
                                void* __restrict__ out, int n_nodes,
                                const int* __restrict__ flags) {
    __shared__ float Ws[HID * OUTD];
    __shared__ float bs[OUTD];
    const int xf32 = flags[1], wf32 = flags[2];
    if (threadIdx.x < HID * OUTD)
        Ws[threadIdx.x] = wf32 ? ((const float*)W2p)[threadIdx.x]
                               : bf2f(((const unsigned short*)W2p)[threadIdx.x]);
    if (threadIdx.x < OUTD)
        bs[threadIdx.x] = wf32 ? ((const float*)b2p)[threadIdx.x]
                               : bf2f(((const unsigned short*)b2p)[threadIdx.x]);
    __syncthreads();

    int t = blockIdx.x * blockDim.x + threadIdx.x;
    int node = t >> 2;
    if (node >= n_nodes) return;
    int q = t & 3;
    v4f a = gather_bf16(h, csr_src, row_off[node], row_off[node + 1], q);

    float o[OUTD];
#pragma unroll
    for (int od = 0; od < OUTD; ++od) {
        float s = 0.f;
#pragma unroll
        for (int j = 0; j < 4; ++j)
            s = fmaf(a[j], Ws[(q * 4 + j) * OUTD + od], s);
        o[od] = s;
    }
#pragma unroll
    for (int od = 0; od < OUTD; ++od) {
        o[od] += __shfl_xor(o[od], 1);
        o[od] += __shfl_xor(o[od], 2);
        o[od] += bs[od];
    }

    if (xf32) {
        float2* po = (float2*)((float*)out + (size_t)node * OUTD);
        if (q == 0) {
            po[0] = make_float2(o[0], o[1]);
            po[1] = make_float2(o[2], o[3]);
        } else if (q == 1) {
            po[2] = make_float2(o[4], o[5]);
            po[3] = make_float2(o[6], o[7]);
        } else if (q == 2) {
            po[4] = make_float2(o[8], o[9]);
        }
    } else {
        unsigned int* po = (unsigned int*)((unsigned short*)out + (size_t)node * OUTD);
        if (q == 0) {
            po[0] = (unsigned int)f2bf(o[0]) | ((unsigned int)f2bf(o[1]) << 16);
            po[1] = (unsigned int)f2bf(o[2]) | ((unsigned int)f2bf(o[3]) << 16);
        } else if (q == 1) {
            po[2] = (unsigned int)f2bf(o[4]) | ((unsigned int)f2bf(o[5]) << 16);
            po[3] = (unsigned int)f2bf(o[6]) | ((unsigned int)f2bf(o[7]) << 16);
        } else if (q == 2) {
            po[4] = (unsigned int)f2bf(o[8]) | ((unsigned int)f2bf(o[9]) << 16);
        }
    }
}

// ---------------- Sentinel: ws_size too small -------------------------------
__global__ void sentinel_kernel(float* __restrict__ out) {
    if (blockIdx.x == 0 && threadIdx.x < 16) out[threadIdx.x] = 123456.0f;
}

extern "C" void kernel_launch(void* const* d_in, const int* in_sizes, int n_in,
                              void* d_out, int out_size, void* d_ws, size_t ws_size,
                              hipStream_t stream) {
    const void* x  = d_in[0];
    const void* ei = d_in[1];
    const void* W1 = d_in[2];
    const void* b1 = d_in[3];
    const void* W2 = d_in[4];
    const void* b2 = d_in[5];

    const int n_nodes = in_sizes[0] / IN_DIM;        // 100000
    const int n_edges = in_sizes[1] / 2;             // 3200000
    const int K = (n_nodes + BKT_W - 1) / BKT_W;     // 391 buckets
    const int x_bytes = in_sizes[0];                 // dtype-agnostic byte count? (see note)

    // NOTE: in_sizes[0] is the element count scaled for bf16 in the harness'
    // convention (size/IN_DIM = n_nodes holds for both dtypes); for prefetch
    // purposes we want the byte range. For fp32 x the buffer is
    // n_nodes*IN_DIM*4 bytes; for bf16 it is *2. We conservatively prefetch
    // the fp32-sized range only when xf32 — but flags aren't known on host.
    // Touching n_nodes*IN_DIM*4 bytes is safe for fp32 and touches 2x the
    // bf16 buffer (overrun!). So prefetch exactly in_sizes[0] bytes, which
    // the harness defines as the true buffer size.
    // (in_sizes[0] / IN_DIM == n_nodes implies in_sizes[0] counts elements
    //  at 1B? Prior rounds derived n_nodes = in_sizes[0]/IN_DIM with fp32
    //  data => in_sizes[0] is element-count-like. Prefetch uses
    //  min(in_sizes[0]*4, that) — keep exactly what gemm will read:
    //  n_nodes*IN_DIM*4 for fp32. We clamp to fp32 size; for bf16 inputs
    //  the x buffer is at least n_nodes*IN_DIM*2 and the prefetch would
    //  overrun — so we prefetch only the bf16-safe half when unsure.)
    const int pref_bytes = n_nodes * IN_DIM * 2;     // safe lower bound both dtypes

    // Workspace layout (256B-aligned). gemm1 overlaps part -> m1/h do not
    // alias pairs.
    char* p = (char*)d_ws;
    auto align = [](size_t v) { return (v + 255) & ~(size_t)255; };
    size_t off = 0;
    int* flags      = (int*)(p + off); off = align(off + 256);
    unsigned short* w1split = (unsigned short*)(p + off); off = align(off + 8192 * 2);
    int* bucket_cnt = (int*)(p + off); off = align(off + (size_t)K * 4);
    int* bucket_off = (int*)(p + off); off = align(off + ((size_t)K + 1) * 4);
    int* bcur       = (int*)(p + off); off = align(off + (size_t)K * 4);
    int* row_off    = (int*)(p + off); off = align(off + ((size_t)n_nodes + 1) * 4);
    int* csr_src    = (int*)(p + off); off = align(off + (size_t)n_edges * 4);
    unsigned int* pairs = (unsigned int*)(p + off); off = align(off + (size_t)n_edges * 4);
    unsigned short* m1 = (unsigned short*)(p + off); off = align(off + (size_t)n_nodes * HID * 2);
    unsigned short* h  = (unsigned short*)(p + off); off = align(off + (size_t)n_nodes * HID * 2);

    if (ws_size < off) {
        sentinel_kernel<<<1, 64, 0, stream>>>((float*)d_out);
        return;
    }

    const int n_tiles16 = (n_nodes + 15) >> 4;        // 6250
    const int g_gemm = (n_tiles16 + 7) / 8;           // 782 (1 tile/wave, 8 waves)
    const int g_part = (n_edges + PART_CH - 1) / PART_CH;  // 391

    // 0. zero bucket counters
    zero_kernel<<<1, 256, 0, stream>>>(bucket_cnt, K);

    // 1. K1 fat: flags + W1 split + bucket histogram + x L3-prefetch
    setup_bhist_kernel<<<17 + G_HIST + G_PREF, 256, 0, stream>>>(
        x, W1, ei, n_nodes, n_edges, pref_bytes, flags, bucket_cnt, K, w1split);

    // 2. bucket scan
    bscan_kernel<<<1, 256, 0, stream>>>(bucket_cnt, K, bucket_off, bcur,
                                        row_off, n_nodes, n_edges);

    // 3. K2 fat: partition overlapped with gemm1 (512-thread blocks)
    part_gemm1_kernel<<<g_part + g_gemm, 512, 0, stream>>>(
        ei, n_edges, bcur, pairs, x, w1split, m1, n_nodes, flags, K, g_part);

    // 4. K3: per-bucket CSR build + layer-1 aggregation fused (1024 thr)
    csr_agg1_kernel<<<K, 1024, 0, stream>>>(pairs, bucket_off, m1, b1,
                                            row_off, csr_src, h, n_nodes, flags);

    // 5. layer 2 aggregation + output GEMM fused
    {
        long long threads = (long long)n_nodes * 4;
        agg2_out_kernel<<<(int)((threads + 255) / 256), 256, 0, stream>>>(
            h, row_off, csr_src, W2, b2, d_out, n_nodes, flags);
    }
}